// Round 1
// 2129.641 us; speedup vs baseline: 1.0675x; 1.0675x over previous
//
#include <hip/hip_runtime.h>
#include <hip/hip_fp16.h>
#include <cstdint>

// ---------------------------------------------------------------------------
// Multi-stream Mamba2-ish LM forward on gfx950.
// All big matmuls: f16 MFMA (16x16x32), f32 accumulate.
// Scan: chunked SSD (chunk Q=64): intra-chunk matmuls + cross-chunk recurrence.
// ---------------------------------------------------------------------------

typedef _Float16 f16;
typedef __attribute__((ext_vector_type(8))) _Float16 f16x8;
typedef __attribute__((ext_vector_type(4))) _Float16 f16x4;
typedef __attribute__((ext_vector_type(4))) float f32x4;

#define LDS_CAST(p) ((__attribute__((address_space(3))) void*)(p))
#define GLB_CAST(p) ((const __attribute__((address_space(1))) void*)(p))

static __device__ __forceinline__ void gload16(const void* g, void* l) {
    __builtin_amdgcn_global_load_lds(GLB_CAST(g), LDS_CAST(l), 16, 0, 0);
}

// ---------------------------------------------------------------------------
// Generic f16 GEMM: C(MxN,f32) = A(MxK,f16) @ Bt(NpadxK,f16)^T + bias
// m97-style: 128x128 tile, BK=32, 4 waves, each wave 64x64 (4x4 MFMA tiles).
// grid: x = M-tiles, y = N-tiles.
// Tile order: GROUP_M=8 grouped (m-fast inner, so 8 consecutive blocks share a
// B-panel and the 8x256KB A-set stays L2-resident) + m204 bijective XCD chunk
// swizzle so each XCD's L2 sees a contiguous run.
// Epilogue: operand-swapped MFMA -> acc regs are 4 consecutive N elements ->
// float4 stores (full 64B segments per wave-store instead of 4x scalar).
// ---------------------------------------------------------------------------
__global__ __launch_bounds__(256) void gemm_f16(
    const f16* __restrict__ A, const f16* __restrict__ Bt,
    const float* __restrict__ bias, float* __restrict__ C,
    int M, int N, int K)
{
    __shared__ f16 As[128 * 32];
    __shared__ f16 Bs[128 * 32];
    const int t = threadIdx.x;
    const int lane = t & 63;
    const int w = t >> 6;

    // ---- tile-order swizzle -------------------------------------------------
    const int gx = gridDim.x;            // M tiles
    const int gy = gridDim.y;            // N tiles
    const int nwg = gx * gy;
    int lin = blockIdx.y * gx + blockIdx.x;
    // m204 bijective XCD chunking (8 XCDs)
    int xcd = lin & 7, loc = lin >> 3;
    int q = nwg >> 3, rr = nwg & 7;
    int wg = (xcd < rr) ? (xcd * (q + 1) + loc)
                        : (rr * (q + 1) + (xcd - rr) * q + loc);
    // grouped ordering: groups of 8 m-tiles, m-fast inner, n walks slow
    const int GROUP = 8;
    int per_group = GROUP * gy;
    int gid = wg / per_group;
    int first_m = gid * GROUP;
    int gsz = (gx - first_m < GROUP) ? (gx - first_m) : GROUP;
    int inner = wg - gid * per_group;
    const int m0 = (first_m + inner % gsz) * 128;
    const int n0 = (inner / gsz) * 128;
    // ------------------------------------------------------------------------

    const int wm0 = (w >> 1) * 64, wn0 = (w & 1) * 64;
    const int mrow = lane & 15, ksel = lane >> 4;

    f32x4 zero = {0.f, 0.f, 0.f, 0.f};
    f32x4 acc[4][4];
#pragma unroll
    for (int i = 0; i < 4; i++)
#pragma unroll
        for (int j = 0; j < 4; j++) acc[i][j] = zero;

    const f16* Abase = A + (size_t)m0 * K;
    const f16* Bbase = Bt + (size_t)n0 * K;

    for (int k0 = 0; k0 < K; k0 += 32) {
#pragma unroll
        for (int i = 0; i < 2; i++) {
            int lin2 = t + i * 256;
            int r = lin2 >> 2;
            int cc = (lin2 & 3) * 8;
            gload16(Abase + (size_t)r * K + k0 + cc, As + lin2 * 8);
            gload16(Bbase + (size_t)r * K + k0 + cc, Bs + lin2 * 8);
        }
        __syncthreads();
        f16x8 af[4], bf[4];
#pragma unroll
        for (int i = 0; i < 4; i++) {
            af[i] = *(const f16x8*)(As + (wm0 + i * 16 + mrow) * 32 + ksel * 8);
            bf[i] = *(const f16x8*)(Bs + (wn0 + i * 16 + mrow) * 32 + ksel * 8);
        }
        // swapped operands: D rows = N-frag, cols = M-frag -> reg index walks N
#pragma unroll
        for (int i = 0; i < 4; i++)
#pragma unroll
            for (int j = 0; j < 4; j++)
                acc[i][j] = __builtin_amdgcn_mfma_f32_16x16x32_f16(bf[j], af[i], acc[i][j], 0, 0, 0);
        __syncthreads();
    }

    // epilogue: thread owns (m = i-tile row via mrow, n..n+3 = j-tile via ksel*4)
#pragma unroll
    for (int i = 0; i < 4; i++) {
        int m = m0 + wm0 + i * 16 + mrow;
#pragma unroll
        for (int j = 0; j < 4; j++) {
            int nb = n0 + wn0 + j * 16 + ksel * 4;
            if (nb < N) {  // N is always a multiple of 4 here
                float4 bv = {0.f, 0.f, 0.f, 0.f};
                if (bias) bv = *(const float4*)(bias + nb);
                float4 v;
                v.x = acc[i][j][0] + bv.x;
                v.y = acc[i][j][1] + bv.y;
                v.z = acc[i][j][2] + bv.z;
                v.w = acc[i][j][3] + bv.w;
                *(float4*)(C + (size_t)m * N + nb) = v;
            }
        }
    }
}

// ---------------------------------------------------------------------------
// Weight convert+transpose: W(KxN,f32) -> Wt(NpadxK,f16), zero-filled pad rows.
// ---------------------------------------------------------------------------
__global__ __launch_bounds__(256) void transpose_w(
    const float* __restrict__ W, f16* __restrict__ Wt, int K, int N, int Npad)
{
    __shared__ float tile[32][33];
    int n0 = blockIdx.x * 32, k0 = blockIdx.y * 32;
    int tx = threadIdx.x & 31, ty = threadIdx.x >> 5;
#pragma unroll
    for (int i = 0; i < 4; i++) {
        int k = k0 + ty + 8 * i;
        int n = n0 + tx;
        tile[ty + 8 * i][tx] = (n < N) ? W[(size_t)k * N + n] : 0.f;
    }
    __syncthreads();
#pragma unroll
    for (int i = 0; i < 4; i++) {
        int n = n0 + ty + 8 * i;
        if (n < Npad) Wt[(size_t)n * K + k0 + tx] = (f16)tile[tx][ty + 8 * i];
    }
}

// ---------------------------------------------------------------------------
// Sinkhorn on 4x4 mixer logits, all 4 layers; single thread (trivial work).
// ---------------------------------------------------------------------------
__global__ void sinkhorn_k(const float* __restrict__ logits, float* __restrict__ Mout)
{
    if (threadIdx.x != 0 || blockIdx.x != 0) return;
    for (int l = 0; l < 4; l++) {
        float M[16];
        for (int i = 0; i < 16; i++) {
            float v = logits[l * 16 + i];
            M[i] = 1.f / (1.f + __expf(-v)) + ((i % 5) == 0 ? 1.f : 0.f);
        }
        for (int it = 0; it < 5; it++) {
            for (int r = 0; r < 4; r++) {
                float s = M[r*4] + M[r*4+1] + M[r*4+2] + M[r*4+3] + 1e-6f;
                for (int c = 0; c < 4; c++) M[r*4+c] /= s;
            }
            for (int c = 0; c < 4; c++) {
                float s = M[c] + M[4+c] + M[8+c] + M[12+c] + 1e-6f;
                for (int r = 0; r < 4; r++) M[r*4+c] /= s;
            }
        }
        for (int i = 0; i < 16; i++) Mout[l * 16 + i] = M[i];
    }
}

__global__ __launch_bounds__(256) void embed_gather(
    const int* __restrict__ tokens, const float* __restrict__ embed, float* __restrict__ H)
{
    int i = blockIdx.x * 256 + threadIdx.x;
    int tok = i >> 8, d4 = i & 255;
    int tk = tokens[tok];
    float4 v = ((const float4*)(embed + (size_t)tk * 1024))[d4];
    ((float4*)(H + (size_t)tok * 1024))[d4] = v;
}

// RMSNorm over d=1024, one block per token, f16 output for GEMM A-operand.
__global__ __launch_bounds__(256) void rmsnorm_k(
    const float* __restrict__ X, const float* __restrict__ w, f16* __restrict__ out)
{
    int tok = blockIdx.x;
    int t = threadIdx.x;
    const float4 v = ((const float4*)(X + (size_t)tok * 1024))[t];
    float ss = v.x*v.x + v.y*v.y + v.z*v.z + v.w*v.w;
#pragma unroll
    for (int off = 32; off > 0; off >>= 1) ss += __shfl_down(ss, off, 64);
    __shared__ float wsum[4];
    if ((t & 63) == 0) wsum[t >> 6] = ss;
    __syncthreads();
    float tot = wsum[0] + wsum[1] + wsum[2] + wsum[3];
    float sc = rsqrtf(tot * (1.f / 1024.f) + 1.1920929e-07f);
    const float4 wv = ((const float4*)w)[t];
    f16x4 o;
    o[0] = (f16)(v.x * sc * wv.x);
    o[1] = (f16)(v.y * sc * wv.y);
    o[2] = (f16)(v.z * sc * wv.z);
    o[3] = (f16)(v.w * sc * wv.w);
    ((f16x4*)(out + (size_t)tok * 1024))[t] = o;
}

// ---------------------------------------------------------------------------
// dt = softplus(dt_raw + bias); cum = inclusive prefix of dt*A per (b,h);
// E[c] = cum at chunk ends. One block per (b,h).
// ---------------------------------------------------------------------------
__global__ __launch_bounds__(256) void dt_cumsum(
    const float* __restrict__ zx, const float* __restrict__ dt_bias,
    const float* __restrict__ A_log,
    float* __restrict__ dt, float* __restrict__ cum, float* __restrict__ E)
{
    int bh = blockIdx.x;
    int b = bh >> 2, h = bh & 3;
    int t = threadIdx.x;
    float Ah = -__expf(A_log[h]);
    float bias = dt_bias[h];
    float run = 0.f, vals[8];
    for (int i = 0; i < 8; i++) {
        int l = t * 8 + i;
        float raw = zx[((size_t)(b * 2048 + l)) * 4612 + 4096 + h] + bias;
        float dtv = (raw > 20.f) ? raw : log1pf(__expf(raw));
        dt[bh * 2048 + l] = dtv;
        run += dtv * Ah;
        vals[i] = run;
    }
    __shared__ float ps[256];
    ps[t] = run;
    __syncthreads();
    for (int off = 1; off < 256; off <<= 1) {
        float v = (t >= off) ? ps[t - off] : 0.f;
        __syncthreads();
        ps[t] += v;
        __syncthreads();
    }
    float offset = (t > 0) ? ps[t - 1] : 0.f;
    // note ps[t] now inclusive incl own run; offset = exclusive
    for (int i = 0; i < 8; i++) {
        int l = t * 8 + i;
        float cv = vals[i] + offset;
        cum[bh * 2048 + l] = cv;
        if ((l & 63) == 63) E[bh * 32 + (l >> 6)] = cv;
    }
}

// x slice of zxbcdt (f32) -> xT (B,H,P,L) f16 (transposed, L-contiguous)
__global__ __launch_bounds__(256) void make_xT(
    const float* __restrict__ zx, f16* __restrict__ xT)
{
    int lb = blockIdx.x * 64, pb = blockIdx.y * 64, bh = blockIdx.z;
    int b = bh >> 2, h = bh & 3;
    __shared__ float tile[64][65];
    int tx = threadIdx.x & 63, ty = threadIdx.x >> 6; // 64 x 4
#pragma unroll
    for (int i = 0; i < 16; i++) {
        int ll = ty + 4 * i;
        tile[ll][tx] = zx[((size_t)(b * 2048 + lb + ll)) * 4612 + 2048 + h * 512 + pb + tx];
    }
    __syncthreads();
#pragma unroll
    for (int i = 0; i < 16; i++) {
        int pl = ty + 4 * i;
        xT[((size_t)bh * 512 + pb + pl) * 2048 + lb + tx] = (f16)tile[tx][pl];
    }
}

// B,C slices -> (B,H,L,64) f16
__global__ __launch_bounds__(256) void make_BC(
    const float* __restrict__ zx, f16* __restrict__ Bc, f16* __restrict__ Cc)
{
    int i = blockIdx.x * 256 + threadIdx.x; // over B*L*H*64 = 1M
    int n = i & 63, h = (i >> 6) & 3, l = (i >> 8) & 2047, b = i >> 19;
    size_t rowoff = ((size_t)(b * 2048 + l)) * 4612 + 4100 + h * 128;
    size_t o = (((size_t)(b * 4 + h)) * 2048 + l) * 64 + n;
    Bc[o] = (f16)zx[rowoff + n];
    Cc[o] = (f16)zx[rowoff + 64 + n];
}

// ---------------------------------------------------------------------------
// Intra-chunk: per (c, bh) block.
//   S[t][s] = (s<=t) ? (C_t.B_s)*exp(cum_t-cum_s)*dt_s : 0
//   W[n][s] = B_s[n]*exp(cumEnd-cum_s)*dt_s
//   Y_intra = S @ X   (64x64 @ 64x512)
//   Hloc    = W @ X   (64x64 @ 64x512)
// S's 64x64x64 dot-product block is done with MFMA (8 per wave), NOT the
// scalar LDS dot loop (2048 conflicted ds_read_u16/thread).
// ---------------------------------------------------------------------------
__global__ __launch_bounds__(256) void chunk_intra(
    const f16* __restrict__ Bc, const f16* __restrict__ Cc,
    const f16* __restrict__ xT,
    const float* __restrict__ dt, const float* __restrict__ cum,
    float* __restrict__ Y, float* __restrict__ Hloc)
{
    int c = blockIdx.x, bh = blockIdx.y;
    int l0 = c * 64;
    __shared__ f16 Cs[4096], Bs2[4096], Sb[4096], Wb[4096];
    __shared__ float cums[64], dts[64];
    int t = threadIdx.x;
    {
        const f16x8* sC = (const f16x8*)(Cc + ((size_t)bh * 2048 + l0) * 64);
        const f16x8* sB = (const f16x8*)(Bc + ((size_t)bh * 2048 + l0) * 64);
        ((f16x8*)Cs)[t] = sC[t];
        ((f16x8*)Cs)[t + 256] = sC[t + 256];
        ((f16x8*)Bs2)[t] = sB[t];
        ((f16x8*)Bs2)[t + 256] = sB[t + 256];
    }
    if (t < 64) {
        cums[t] = cum[bh * 2048 + l0 + t];
        dts[t] = dt[bh * 2048 + l0 + t];
    }
    __syncthreads();
    float cumEnd = cums[63];
    int lane = t & 63, w = t >> 6;
    int mrow = lane & 15, ksel = lane >> 4;

    // ---- S = tril(C @ B^T) * decay via MFMA; wave w owns rows w*16..w*16+15
    {
        f16x8 cf[2];
        cf[0] = *(const f16x8*)(Cs + (w * 16 + mrow) * 64 + ksel * 8);
        cf[1] = *(const f16x8*)(Cs + (w * 16 + mrow) * 64 + 32 + ksel * 8);
#pragma unroll
        for (int j = 0; j < 4; j++) {
            f32x4 d = {0.f, 0.f, 0.f, 0.f};
#pragma unroll
            for (int ks = 0; ks < 2; ks++) {
                f16x8 bfv = *(const f16x8*)(Bs2 + (j * 16 + mrow) * 64 + ks * 32 + ksel * 8);
                d = __builtin_amdgcn_mfma_f32_16x16x32_f16(cf[ks], bfv, d, 0, 0, 0);
            }
            int ss = j * 16 + mrow;
#pragma unroll
            for (int r = 0; r < 4; r++) {
                int tt = w * 16 + ksel * 4 + r;
                float sv = (ss <= tt) ? d[r] * __expf(cums[tt] - cums[ss]) * dts[ss] : 0.f;
                Sb[tt * 64 + ss] = (f16)sv;
            }
        }
        // W is elementwise from B (no dot product): 16 entries per thread
#pragma unroll
        for (int q2 = 0; q2 < 16; q2++) {
            int idx = t * 16 + q2;
            int tt = idx >> 6, ss = idx & 63;
            float wv = (float)Bs2[ss * 64 + tt] * __expf(cumEnd - cums[ss]) * dts[ss];
            Wb[tt * 64 + ss] = (f16)wv;
        }
    }
    __syncthreads();

    f16x8 sfr[2][4], wfr[2][4];
#pragma unroll
    for (int ks = 0; ks < 2; ks++)
#pragma unroll
        for (int mt = 0; mt < 4; mt++) {
            sfr[ks][mt] = *(const f16x8*)(Sb + (mt * 16 + mrow) * 64 + ks * 32 + ksel * 8);
            wfr[ks][mt] = *(const f16x8*)(Wb + (mt * 16 + mrow) * 64 + ks * 32 + ksel * 8);
        }
    const f16* xbase = xT + ((size_t)bh * 512) * 2048 + c * 64;
    f32x4 zero = {0.f, 0.f, 0.f, 0.f};
#pragma unroll
    for (int ph = 0; ph < 2; ph++) {
        int pb = w * 128 + ph * 64;
        f32x4 aY[4][4], aH[4][4];
#pragma unroll
        for (int i = 0; i < 4; i++)
#pragma unroll
            for (int j = 0; j < 4; j++) { aY[i][j] = zero; aH[i][j] = zero; }
#pragma unroll
        for (int ks = 0; ks < 2; ks++) {
#pragma unroll
            for (int nt = 0; nt < 4; nt++) {
                int pp = pb + nt * 16 + mrow;
                f16x8 bfv = *(const f16x8*)(xbase + (size_t)pp * 2048 + ks * 32 + ksel * 8);
#pragma unroll
                for (int mt = 0; mt < 4; mt++) {
                    aY[mt][nt] = __builtin_amdgcn_mfma_f32_16x16x32_f16(sfr[ks][mt], bfv, aY[mt][nt], 0, 0, 0);
                    aH[mt][nt] = __builtin_amdgcn_mfma_f32_16x16x32_f16(wfr[ks][mt], bfv, aH[mt][nt], 0, 0, 0);
                }
            }
        }
        int r0 = ksel * 4;
#pragma unroll
        for (int mt = 0; mt < 4; mt++)
#pragma unroll
            for (int nt = 0; nt < 4; nt++) {
                int pp = pb + nt * 16 + mrow;
#pragma unroll
                for (int r = 0; r < 4; r++) {
                    int tt = mt * 16 + r0 + r;
                    Y[((size_t)bh * 2048 + l0 + tt) * 512 + pp] = aY[mt][nt][r];
                    Hloc[(((size_t)bh * 32 + c) * 64 + tt) * 512 + pp] = aH[mt][nt][r];
                }
            }
    }
}

// ---------------------------------------------------------------------------
// Cross-chunk recurrence. Thread owns (p, 4 n's) of one bh. Writes the state
// BEFORE chunk c as HpreT (BH,32,512,64) f16. grid (8 p-blocks, 8 bh, 4 n-quads)
// = 256 blocks (full CU coverage; previous version used 64 blocks).
// ---------------------------------------------------------------------------
__global__ __launch_bounds__(256) void chunk_scan(
    const float* __restrict__ Hloc, const float* __restrict__ E,
    f16* __restrict__ HpreT)
{
    int bh = blockIdx.y;
    int p = blockIdx.x * 64 + (threadIdx.x & 63);
    int nb = blockIdx.z * 16 + (threadIdx.x >> 6) * 4;
    float h[4];
#pragma unroll
    for (int j = 0; j < 4; j++) h[j] = 0.f;
    float Eprev = 0.f;
    for (int c = 0; c < 32; c++) {
        size_t ob = (((size_t)bh * 32 + c) * 512 + p) * 64 + nb;
        f16x4 v;
#pragma unroll
        for (int j = 0; j < 4; j++) v[j] = (f16)h[j];
        *(f16x4*)(HpreT + ob) = v;
        float Ec = E[bh * 32 + c];
        float decay = __expf(Ec - Eprev);
        Eprev = Ec;
        size_t ib = (((size_t)bh * 32 + c) * 64 + nb) * 512 + p;
#pragma unroll
        for (int j = 0; j < 4; j++)
            h[j] = decay * h[j] + Hloc[ib + (size_t)j * 512];
    }
}

// ---------------------------------------------------------------------------
// Inter-chunk Y += Chat @ Hpre, then fused epilogue:
//   y = Y_intra + Y_inter + x*D; out = y * silu(z)  -> ybuf f16 (B*L, 2048)
// ---------------------------------------------------------------------------
__global__ __launch_bounds__(256) void chunk_inter(
    const f16* __restrict__ Cc, const f16* __restrict__ HpreT,
    const float* __restrict__ cum, const float* __restrict__ E,
    const float* __restrict__ Y, const float* __restrict__ zx,
    const float* __restrict__ Dp, f16* __restrict__ ybuf)
{
    int c = blockIdx.x, bh = blockIdx.y;
    int b = bh >> 2, h = bh & 3;
    int l0 = c * 64;
    __shared__ f16 Chat[4096];
    int t = threadIdx.x;
    float Eprev = (c > 0) ? E[bh * 32 + c - 1] : 0.f;
    for (int i = t; i < 4096; i += 256) {
        int tt = i >> 6, n = i & 63;
        float cv = (float)Cc[((size_t)bh * 2048 + l0 + tt) * 64 + n];
        Chat[i] = (f16)(cv * __expf(cum[bh * 2048 + l0 + tt] - Eprev));
    }
    __syncthreads();
    int lane = t & 63, w = t >> 6;
    int mrow = lane & 15, ksel = lane >> 4;
    float Dh = Dp[h];
    f16x8 af[2][4];
#pragma unroll
    for (int ks = 0; ks < 2; ks++)
#pragma unroll
        for (int mt = 0; mt < 4; mt++)
            af[ks][mt] = *(const f16x8*)(Chat + (mt * 16 + mrow) * 64 + ks * 32 + ksel * 8);
    const f16* hb = HpreT + (((size_t)bh * 32 + c) * 512) * 64;
    f32x4 zero = {0.f, 0.f, 0.f, 0.f};
#pragma unroll
    for (int ph = 0; ph < 2; ph++) {
        int pb = w * 128 + ph * 64;
        f32x4 acc[4][4];
#pragma unroll
        for (int i = 0; i < 4; i++)
#pragma unroll
            for (int j = 0; j < 4; j++) acc[i][j] = zero;
#pragma unroll
        for (int ks = 0; ks < 2; ks++) {
#pragma unroll
            for (int nt = 0; nt < 4; nt++) {
                int pp = pb + nt * 16 + mrow;
                f16x8 bfv = *(const f16x8*)(hb + (size_t)pp * 64 + ks * 32 + ksel * 8);
#pragma unroll
                for (int mt = 0; mt < 4; mt++)
                    acc[mt][nt] = __builtin_amdgcn_mfma_f32_16x16x32_f16(af[ks][mt], bfv, acc[mt][nt], 0, 0, 0);
            }
        }
        int r0 = ksel * 4;
#pragma unroll
        for (int mt = 0; mt < 4; mt++)
#pragma unroll
            for (int nt = 0; nt < 4; nt++) {
                int pp = pb + nt * 16 + mrow;
#pragma unroll
                for (int r = 0; r < 4; r++) {
                    int tt = mt * 16 + r0 + r;
                    int l = l0 + tt;
                    size_t zrow = ((size_t)(b * 2048 + l)) * 4612;
                    float y = acc[mt][nt][r] + Y[((size_t)bh * 2048 + l) * 512 + pp];
                    float x = zx[zrow + 2048 + h * 512 + pp];
                    y += x * Dh;
                    float z = zx[zrow + h * 512 + pp];
                    float sig = 1.f / (1.f + __expf(-z));
                    ybuf[((size_t)(b * 2048 + l)) * 2048 + h * 512 + pp] = (f16)(y * z * sig);
                }
            }
    }
}

// H_new[tok, s*256+j] = sum_i M[s][i]*H_old[tok, i*256+j] + xout[tok, s*256+j]
__global__ __launch_bounds__(256) void mix_add(
    const float* __restrict__ Hold, const float* __restrict__ xout,
    const float* __restrict__ Mm, float* __restrict__ Hnew)
{
    int i = blockIdx.x * 256 + threadIdx.x;
    int j = i & 255, tok = i >> 8;
    size_t rb = (size_t)tok * 1024;
    float h0 = Hold[rb + j], h1 = Hold[rb + 256 + j];
    float h2 = Hold[rb + 512 + j], h3 = Hold[rb + 768 + j];
#pragma unroll
    for (int s = 0; s < 4; s++) {
        float v = Mm[s*4+0]*h0 + Mm[s*4+1]*h1 + Mm[s*4+2]*h2 + Mm[s*4+3]*h3
                + xout[rb + s * 256 + j];
        Hnew[rb + s * 256 + j] = v;
    }
}

// ---------------------------------------------------------------------------
extern "C" void kernel_launch(void* const* d_in, const int* in_sizes, int n_in,
                              void* d_out, int out_size, void* d_ws, size_t ws_size,
                              hipStream_t stream)
{
    const int*   tokens     = (const int*)d_in[0];
    const float* embed      = (const float*)d_in[1];
    const float* norm_w     = (const float*)d_in[2];
    const float* in_proj_W  = (const float*)d_in[3];
    const float* in_proj_b  = (const float*)d_in[4];
    const float* A_log      = (const float*)d_in[5];
    const float* Dp         = (const float*)d_in[6];
    const float* dt_bias    = (const float*)d_in[7];
    const float* out_proj_W = (const float*)d_in[8];
    const float* out_proj_b = (const float*)d_in[9];
    const float* mixer_log  = (const float*)d_in[10];
    const float* norm_f_w   = (const float*)d_in[11];
    const float* head_W     = (const float*)d_in[12];
    const float* head_b     = (const float*)d_in[13];
    float* out = (float*)d_out;
    (void)in_sizes; (void)n_in; (void)out_size; (void)ws_size;

    char* base = (char*)d_ws;
    size_t off = 0;
    auto alloc = [&](size_t bytes) -> void* {
        void* r = (void*)(base + off);
        off = (off + bytes + 255) & ~(size_t)255;
        return r;
    };
    f16*   WinT   = (f16*)alloc(4ull * 4736 * 1024 * 2);
    f16*   WoutT  = (f16*)alloc(4ull * 1024 * 2048 * 2);
    f16*   WheadT = (f16*)alloc(32000ull * 1024 * 2);
    float* Mall   = (float*)alloc(64 * 4);
    float* H0     = (float*)alloc(4096ull * 1024 * 4);
    float* H1     = (float*)alloc(4096ull * 1024 * 4);
    f16*   un     = (f16*)alloc(4096ull * 1024 * 2);   // also reused as final fh
    float* zx     = (float*)alloc(4096ull * 4612 * 4);
    float* dtb    = (float*)alloc(8ull * 2048 * 4);
    float* cumb   = (float*)alloc(8ull * 2048 * 4);
    float* Eb     = (float*)alloc(8ull * 32 * 4);
    f16*   xT     = (f16*)alloc(8ull * 512 * 2048 * 2);
    f16*   Bc     = (f16*)alloc(8ull * 2048 * 64 * 2);
    f16*   Cc     = (f16*)alloc(8ull * 2048 * 64 * 2);
    float* Yb     = (float*)alloc(8ull * 2048 * 512 * 4);
    float* Hloc   = (float*)alloc(8ull * 32 * 64 * 512 * 4);
    f16*   HpreT  = (f16*)alloc(8ull * 32 * 512 * 64 * 2);
    f16*   ybuf   = (f16*)alloc(4096ull * 2048 * 2);
    float* xout   = (float*)alloc(4096ull * 1024 * 4);

    // Weight conversion (every call; inputs are re-restored by harness)
    for (int l = 0; l < 4; l++) {
        transpose_w<<<dim3(148, 32), 256, 0, stream>>>(
            in_proj_W + (size_t)l * 1024 * 4612, WinT + (size_t)l * 4736 * 1024,
            1024, 4612, 4736);
        transpose_w<<<dim3(32, 64), 256, 0, stream>>>(
            out_proj_W + (size_t)l * 2048 * 1024, WoutT + (size_t)l * 1024 * 2048,
            2048, 1024, 1024);
    }
    transpose_w<<<dim3(1000, 32), 256, 0, stream>>>(head_W, WheadT, 1024, 32000, 32000);
    sinkhorn_k<<<1, 64, 0, stream>>>(mixer_log, Mall);
    embed_gather<<<4096, 256, 0, stream>>>(tokens, embed, H0);

    float* Hc = H0;
    float* Hn = H1;
    for (int l = 0; l < 4; l++) {
        rmsnorm_k<<<4096, 256, 0, stream>>>(Hc, norm_w + l * 1024, un);
        gemm_f16<<<dim3(32, 37), 256, 0, stream>>>(
            un, WinT + (size_t)l * 4736 * 1024, in_proj_b + l * 4612, zx,
            4096, 4612, 1024);
        dt_cumsum<<<8, 256, 0, stream>>>(zx, dt_bias + l * 4, A_log + l * 4, dtb, cumb, Eb);
        make_xT<<<dim3(32, 8, 8), 256, 0, stream>>>(zx, xT);
        make_BC<<<4096, 256, 0, stream>>>(zx, Bc, Cc);
        chunk_intra<<<dim3(32, 8), 256, 0, stream>>>(Bc, Cc, xT, dtb, cumb, Yb, Hloc);
        chunk_scan<<<dim3(8, 8, 4), 256, 0, stream>>>(Hloc, Eb, HpreT);
        chunk_inter<<<dim3(32, 8), 256, 0, stream>>>(Cc, HpreT, cumb, Eb, Yb, zx, Dp + l * 4, ybuf);
        gemm_f16<<<dim3(32, 8), 256, 0, stream>>>(
            ybuf, WoutT + (size_t)l * 1024 * 2048, out_proj_b + l * 1024, xout,
            4096, 1024, 2048);
        mix_add<<<4096, 256, 0, stream>>>(Hc, xout, Mall + l * 16, Hn);
        float* tmp = Hc; Hc = Hn; Hn = tmp;
    }
    rmsnorm_k<<<4096, 256, 0, stream>>>(Hc, norm_f_w, un);
    gemm_f16<<<dim3(32, 250), 256, 0, stream>>>(un, WheadT, head_b, out, 4096, 32000, 1024);
}

// Round 2
// 2099.573 us; speedup vs baseline: 1.0828x; 1.0143x over previous
//
#include <hip/hip_runtime.h>
#include <hip/hip_fp16.h>
#include <cstdint>

// ---------------------------------------------------------------------------
// Multi-stream Mamba2-ish LM forward on gfx950.
// All big matmuls: f16 MFMA (16x16x32), f32 accumulate.
// Scan: chunked SSD (chunk Q=64): intra-chunk matmuls + cross-chunk recurrence.
// ---------------------------------------------------------------------------

typedef _Float16 f16;
typedef __attribute__((ext_vector_type(8))) _Float16 f16x8;
typedef __attribute__((ext_vector_type(4))) _Float16 f16x4;
typedef __attribute__((ext_vector_type(4))) float f32x4;

#define LDS_CAST(p) ((__attribute__((address_space(3))) void*)(p))
#define GLB_CAST(p) ((const __attribute__((address_space(1))) void*)(p))

static __device__ __forceinline__ void gload16(const void* g, void* l) {
    __builtin_amdgcn_global_load_lds(GLB_CAST(g), LDS_CAST(l), 16, 0, 0);
}

// ---------------------------------------------------------------------------
// gemm256: C(MxN,f32) = A(MxK,f16) @ Bt(NxK,f16)^T + bias
// 256x256 tile, BK=32, 512 threads (8 waves, 2M x 4N), per-wave 128x64 out.
// T3+T4: triple-buffered LDS ring, stage 2 K-tiles ahead, 2 phases per K-tile,
// raw s_barrier (no vmcnt(0) drain), one counted s_waitcnt vmcnt(4) per tile.
// T2: 16B-granule XOR swizzle (col16 ^= row&3) on LDS; global source is
// pre-swizzled, global_load_lds dest stays linear (rule 21).
// T5: setprio(1) around each 16-MFMA cluster.
// Requires: M%256==0, Npad%256==0 (zero-padded Bt rows), K%32==0, K>=96.
// ---------------------------------------------------------------------------
__global__ __launch_bounds__(512, 2) void gemm256(
    const f16* __restrict__ A, const f16* __restrict__ Bt,
    const float* __restrict__ bias, float* __restrict__ C,
    int M, int N, int K)
{
    __shared__ f16 AS[3 * 256 * 32];   // 3 slots x (256 rows x 32 f16) = 48KB
    __shared__ f16 BS[3 * 256 * 32];   // 48KB

    const int tid = threadIdx.x;
    const int lane = tid & 63;
    const int w = tid >> 6;
    const int wr = w >> 2;            // 0..1  (M half)
    const int wc = w & 3;             // 0..3  (N quarter)
    const int mrow = lane & 15, ksel = lane >> 4;

    // ---- tile-order swizzle (m204 bijective XCD chunk + GROUP_M=8 m-fast) ---
    const int gx = gridDim.x;         // M tiles
    const int gy = gridDim.y;         // N tiles
    const int nwg = gx * gy;
    int lin = blockIdx.y * gx + blockIdx.x;
    int xcd = lin & 7, loc = lin >> 3;
    int q = nwg >> 3, rr = nwg & 7;
    int wg = (xcd < rr) ? (xcd * (q + 1) + loc)
                        : (rr * (q + 1) + (xcd - rr) * q + loc);
    const int GROUP = 8;
    int per_group = GROUP * gy;
    int gid = wg / per_group;
    int first_m = gid * GROUP;
    int gsz = (gx - first_m < GROUP) ? (gx - first_m) : GROUP;
    int inner = wg - gid * per_group;
    const int m0 = (first_m + inner % gsz) * 256;
    const int n0 = (inner / gsz) * 256;
    // ------------------------------------------------------------------------

    // staging geometry: half-tile = 128 rows x 32 f16 (8KB), 1 gload16/thread.
    // physical LDS cell (row, 16B-chunk c) holds logical chunk c ^ (row&3).
    const int rowt = tid >> 2;                       // 0..127
    const int colE = ((tid & 3) ^ (rowt & 3)) * 8;   // pre-swizzled source col (elems)
    const int ldst = tid * 8;                        // linear LDS dest (elems)

    const f16* gA = A + (size_t)m0 * K;
    const f16* gB = Bt + (size_t)n0 * K;
    const size_t gofsA0 = (size_t)rowt * K + colE;
    const size_t gofsA1 = (size_t)(128 + rowt) * K + colE;
    const size_t gofsB0 = gofsA0;
    const size_t gofsB1 = gofsA1;

    // fragment read offsets (swizzled): row*32 + (ksel ^ (mrow&3))*8
    const int fcol = ((ksel ^ (mrow & 3)) * 8);
    int offA[8], offB[4];
#pragma unroll
    for (int mf = 0; mf < 8; mf++)
        offA[mf] = (wr * 128 + mf * 16 + mrow) * 32 + fcol;
#pragma unroll
    for (int nf = 0; nf < 4; nf++)
        offB[nf] = (wc * 64 + nf * 16 + mrow) * 32 + fcol;

    f32x4 zero = {0.f, 0.f, 0.f, 0.f};
    f32x4 acc[8][4];
#pragma unroll
    for (int i = 0; i < 8; i++)
#pragma unroll
        for (int j = 0; j < 4; j++) acc[i][j] = zero;

    const int nt = K >> 5;

    // ---- prologue: stage tiles 0 and 1 into slots 0,1 -----------------------
#pragma unroll
    for (int T = 0; T < 2; ++T) {
        gload16(gA + gofsA0 + (size_t)T * 32, AS + T * 8192 + ldst);
        gload16(gA + gofsA1 + (size_t)T * 32, AS + T * 8192 + 4096 + ldst);
        gload16(gB + gofsB0 + (size_t)T * 32, BS + T * 8192 + ldst);
        gload16(gB + gofsB1 + (size_t)T * 32, BS + T * 8192 + 4096 + ldst);
    }
    asm volatile("s_waitcnt vmcnt(4)" ::: "memory");  // tile 0 resident
    __builtin_amdgcn_sched_barrier(0);
    __builtin_amdgcn_s_barrier();

    // ---- main loop ----------------------------------------------------------
    for (int t = 0; t < nt; ++t) {
        const int slot = t % 3;
        const f16* as = AS + slot * 8192;
        const f16* bs = BS + slot * 8192;
        const int sst = (t + 2) % 3;
        const bool st = (t + 2) < nt;
        const size_t kof = (size_t)(t + 2) * 32;

        // ---- phase 0: read af[0..3] + bf[0..3]; stage A halves of t+2 -------
        f16x8 af[4], bf[4];
#pragma unroll
        for (int mf = 0; mf < 4; mf++) af[mf] = *(const f16x8*)(as + offA[mf]);
#pragma unroll
        for (int nf = 0; nf < 4; nf++) bf[nf] = *(const f16x8*)(bs + offB[nf]);
        if (st) {
            gload16(gA + gofsA0 + kof, AS + sst * 8192 + ldst);
            gload16(gA + gofsA1 + kof, AS + sst * 8192 + 4096 + ldst);
        }
        __builtin_amdgcn_s_barrier();
        __builtin_amdgcn_s_setprio(1);
#pragma unroll
        for (int mf = 0; mf < 4; mf++)
#pragma unroll
            for (int nf = 0; nf < 4; nf++)
                acc[mf][nf] = __builtin_amdgcn_mfma_f32_16x16x32_f16(bf[nf], af[mf], acc[mf][nf], 0, 0, 0);
        __builtin_amdgcn_s_setprio(0);
        __builtin_amdgcn_s_barrier();

        // ---- phase 1: read af[4..7]; stage B halves of t+2 ------------------
        f16x8 af2[4];
#pragma unroll
        for (int mf = 0; mf < 4; mf++) af2[mf] = *(const f16x8*)(as + offA[4 + mf]);
        if (st) {
            gload16(gB + gofsB0 + kof, BS + sst * 8192 + ldst);
            gload16(gB + gofsB1 + kof, BS + sst * 8192 + 4096 + ldst);
        }
        __builtin_amdgcn_s_barrier();
        __builtin_amdgcn_s_setprio(1);
#pragma unroll
        for (int mf = 0; mf < 4; mf++)
#pragma unroll
            for (int nf = 0; nf < 4; nf++)
                acc[4 + mf][nf] = __builtin_amdgcn_mfma_f32_16x16x32_f16(bf[nf], af2[mf], acc[4 + mf][nf], 0, 0, 0);
        __builtin_amdgcn_s_setprio(0);

        // ---- K-tile boundary: counted drain (never 0 in steady state) -------
        if (t + 1 < nt) {
            if (st) {
                asm volatile("s_waitcnt vmcnt(4)" ::: "memory");
            } else {
                asm volatile("s_waitcnt vmcnt(0)" ::: "memory");
            }
            __builtin_amdgcn_sched_barrier(0);
            __builtin_amdgcn_s_barrier();
        }
    }

    // ---- epilogue: float4 stores (acc regs walk 4 consecutive n) ------------
#pragma unroll
    for (int mf = 0; mf < 8; mf++) {
        int m = m0 + wr * 128 + mf * 16 + mrow;
#pragma unroll
        for (int nf = 0; nf < 4; nf++) {
            int nb = n0 + wc * 64 + nf * 16 + ksel * 4;
            if (nb < N) {
                float4 bv = {0.f, 0.f, 0.f, 0.f};
                if (bias) bv = *(const float4*)(bias + nb);
                float4 v;
                v.x = acc[mf][nf][0] + bv.x;
                v.y = acc[mf][nf][1] + bv.y;
                v.z = acc[mf][nf][2] + bv.z;
                v.w = acc[mf][nf][3] + bv.w;
                *(float4*)(C + (size_t)m * N + nb) = v;
            }
        }
    }
}

// ---------------------------------------------------------------------------
// Generic f16 GEMM (128x128 tile, m97 structure) — kept for out-proj (N=1024).
// ---------------------------------------------------------------------------
__global__ __launch_bounds__(256) void gemm_f16(
    const f16* __restrict__ A, const f16* __restrict__ Bt,
    const float* __restrict__ bias, float* __restrict__ C,
    int M, int N, int K)
{
    __shared__ f16 As[128 * 32];
    __shared__ f16 Bs[128 * 32];
    const int t = threadIdx.x;
    const int lane = t & 63;
    const int w = t >> 6;

    const int gx = gridDim.x;            // M tiles
    const int gy = gridDim.y;            // N tiles
    const int nwg = gx * gy;
    int lin = blockIdx.y * gx + blockIdx.x;
    int xcd = lin & 7, loc = lin >> 3;
    int q = nwg >> 3, rr = nwg & 7;
    int wg = (xcd < rr) ? (xcd * (q + 1) + loc)
                        : (rr * (q + 1) + (xcd - rr) * q + loc);
    const int GROUP = 8;
    int per_group = GROUP * gy;
    int gid = wg / per_group;
    int first_m = gid * GROUP;
    int gsz = (gx - first_m < GROUP) ? (gx - first_m) : GROUP;
    int inner = wg - gid * per_group;
    const int m0 = (first_m + inner % gsz) * 128;
    const int n0 = (inner / gsz) * 128;

    const int wm0 = (w >> 1) * 64, wn0 = (w & 1) * 64;
    const int mrow = lane & 15, ksel = lane >> 4;

    f32x4 zero = {0.f, 0.f, 0.f, 0.f};
    f32x4 acc[4][4];
#pragma unroll
    for (int i = 0; i < 4; i++)
#pragma unroll
        for (int j = 0; j < 4; j++) acc[i][j] = zero;

    const f16* Abase = A + (size_t)m0 * K;
    const f16* Bbase = Bt + (size_t)n0 * K;

    for (int k0 = 0; k0 < K; k0 += 32) {
#pragma unroll
        for (int i = 0; i < 2; i++) {
            int lin2 = t + i * 256;
            int r = lin2 >> 2;
            int cc = (lin2 & 3) * 8;
            gload16(Abase + (size_t)r * K + k0 + cc, As + lin2 * 8);
            gload16(Bbase + (size_t)r * K + k0 + cc, Bs + lin2 * 8);
        }
        __syncthreads();
        f16x8 af[4], bf[4];
#pragma unroll
        for (int i = 0; i < 4; i++) {
            af[i] = *(const f16x8*)(As + (wm0 + i * 16 + mrow) * 32 + ksel * 8);
            bf[i] = *(const f16x8*)(Bs + (wn0 + i * 16 + mrow) * 32 + ksel * 8);
        }
#pragma unroll
        for (int i = 0; i < 4; i++)
#pragma unroll
            for (int j = 0; j < 4; j++)
                acc[i][j] = __builtin_amdgcn_mfma_f32_16x16x32_f16(bf[j], af[i], acc[i][j], 0, 0, 0);
        __syncthreads();
    }

#pragma unroll
    for (int i = 0; i < 4; i++) {
        int m = m0 + wm0 + i * 16 + mrow;
#pragma unroll
        for (int j = 0; j < 4; j++) {
            int nb = n0 + wn0 + j * 16 + ksel * 4;
            if (nb < N) {
                float4 bv = {0.f, 0.f, 0.f, 0.f};
                if (bias) bv = *(const float4*)(bias + nb);
                float4 v;
                v.x = acc[i][j][0] + bv.x;
                v.y = acc[i][j][1] + bv.y;
                v.z = acc[i][j][2] + bv.z;
                v.w = acc[i][j][3] + bv.w;
                *(float4*)(C + (size_t)m * N + nb) = v;
            }
        }
    }
}

// ---------------------------------------------------------------------------
// Weight convert+transpose: W(KxN,f32) -> Wt(NpadxK,f16), zero-filled pad rows.
// ---------------------------------------------------------------------------
__global__ __launch_bounds__(256) void transpose_w(
    const float* __restrict__ W, f16* __restrict__ Wt, int K, int N, int Npad)
{
    __shared__ float tile[32][33];
    int n0 = blockIdx.x * 32, k0 = blockIdx.y * 32;
    int tx = threadIdx.x & 31, ty = threadIdx.x >> 5;
#pragma unroll
    for (int i = 0; i < 4; i++) {
        int k = k0 + ty + 8 * i;
        int n = n0 + tx;
        tile[ty + 8 * i][tx] = (n < N) ? W[(size_t)k * N + n] : 0.f;
    }
    __syncthreads();
#pragma unroll
    for (int i = 0; i < 4; i++) {
        int n = n0 + ty + 8 * i;
        if (n < Npad) Wt[(size_t)n * K + k0 + tx] = (f16)tile[tx][ty + 8 * i];
    }
}

// ---------------------------------------------------------------------------
// Sinkhorn on 4x4 mixer logits, all 4 layers; single thread (trivial work).
// ---------------------------------------------------------------------------
__global__ void sinkhorn_k(const float* __restrict__ logits, float* __restrict__ Mout)
{
    if (threadIdx.x != 0 || blockIdx.x != 0) return;
    for (int l = 0; l < 4; l++) {
        float M[16];
        for (int i = 0; i < 16; i++) {
            float v = logits[l * 16 + i];
            M[i] = 1.f / (1.f + __expf(-v)) + ((i % 5) == 0 ? 1.f : 0.f);
        }
        for (int it = 0; it < 5; it++) {
            for (int r = 0; r < 4; r++) {
                float s = M[r*4] + M[r*4+1] + M[r*4+2] + M[r*4+3] + 1e-6f;
                for (int c = 0; c < 4; c++) M[r*4+c] /= s;
            }
            for (int c = 0; c < 4; c++) {
                float s = M[c] + M[4+c] + M[8+c] + M[12+c] + 1e-6f;
                for (int r = 0; r < 4; r++) M[r*4+c] /= s;
            }
        }
        for (int i = 0; i < 16; i++) Mout[l * 16 + i] = M[i];
    }
}

__global__ __launch_bounds__(256) void embed_gather(
    const int* __restrict__ tokens, const float* __restrict__ embed, float* __restrict__ H)
{
    int i = blockIdx.x * 256 + threadIdx.x;
    int tok = i >> 8, d4 = i & 255;
    int tk = tokens[tok];
    float4 v = ((const float4*)(embed + (size_t)tk * 1024))[d4];
    ((float4*)(H + (size_t)tok * 1024))[d4] = v;
}

// RMSNorm over d=1024, one block per token, f16 output for GEMM A-operand.
__global__ __launch_bounds__(256) void rmsnorm_k(
    const float* __restrict__ X, const float* __restrict__ w, f16* __restrict__ out)
{
    int tok = blockIdx.x;
    int t = threadIdx.x;
    const float4 v = ((const float4*)(X + (size_t)tok * 1024))[t];
    float ss = v.x*v.x + v.y*v.y + v.z*v.z + v.w*v.w;
#pragma unroll
    for (int off = 32; off > 0; off >>= 1) ss += __shfl_down(ss, off, 64);
    __shared__ float wsum[4];
    if ((t & 63) == 0) wsum[t >> 6] = ss;
    __syncthreads();
    float tot = wsum[0] + wsum[1] + wsum[2] + wsum[3];
    float sc = rsqrtf(tot * (1.f / 1024.f) + 1.1920929e-07f);
    const float4 wv = ((const float4*)w)[t];
    f16x4 o;
    o[0] = (f16)(v.x * sc * wv.x);
    o[1] = (f16)(v.y * sc * wv.y);
    o[2] = (f16)(v.z * sc * wv.z);
    o[3] = (f16)(v.w * sc * wv.w);
    ((f16x4*)(out + (size_t)tok * 1024))[t] = o;
}

// ---------------------------------------------------------------------------
// dt = softplus(dt_raw + bias); cum = inclusive prefix of dt*A per (b,h);
// E[c] = cum at chunk ends. One block per (b,h).
// ---------------------------------------------------------------------------
__global__ __launch_bounds__(256) void dt_cumsum(
    const float* __restrict__ zx, const float* __restrict__ dt_bias,
    const float* __restrict__ A_log,
    float* __restrict__ dt, float* __restrict__ cum, float* __restrict__ E)
{
    int bh = blockIdx.x;
    int b = bh >> 2, h = bh & 3;
    int t = threadIdx.x;
    float Ah = -__expf(A_log[h]);
    float bias = dt_bias[h];
    float run = 0.f, vals[8];
    for (int i = 0; i < 8; i++) {
        int l = t * 8 + i;
        float raw = zx[((size_t)(b * 2048 + l)) * 4612 + 4096 + h] + bias;
        float dtv = (raw > 20.f) ? raw : log1pf(__expf(raw));
        dt[bh * 2048 + l] = dtv;
        run += dtv * Ah;
        vals[i] = run;
    }
    __shared__ float ps[256];
    ps[t] = run;
    __syncthreads();
    for (int off = 1; off < 256; off <<= 1) {
        float v = (t >= off) ? ps[t - off] : 0.f;
        __syncthreads();
        ps[t] += v;
        __syncthreads();
    }
    float offset = (t > 0) ? ps[t - 1] : 0.f;
    for (int i = 0; i < 8; i++) {
        int l = t * 8 + i;
        float cv = vals[i] + offset;
        cum[bh * 2048 + l] = cv;
        if ((l & 63) == 63) E[bh * 32 + (l >> 6)] = cv;
    }
}

// x slice of zxbcdt (f32) -> xT (B,H,P,L) f16 (transposed, L-contiguous)
__global__ __launch_bounds__(256) void make_xT(
    const float* __restrict__ zx, f16* __restrict__ xT)
{
    int lb = blockIdx.x * 64, pb = blockIdx.y * 64, bh = blockIdx.z;
    int b = bh >> 2, h = bh & 3;
    __shared__ float tile[64][65];
    int tx = threadIdx.x & 63, ty = threadIdx.x >> 6; // 64 x 4
#pragma unroll
    for (int i = 0; i < 16; i++) {
        int ll = ty + 4 * i;
        tile[ll][tx] = zx[((size_t)(b * 2048 + lb + ll)) * 4612 + 2048 + h * 512 + pb + tx];
    }
    __syncthreads();
#pragma unroll
    for (int i = 0; i < 16; i++) {
        int pl = ty + 4 * i;
        xT[((size_t)bh * 512 + pb + pl) * 2048 + lb + tx] = (f16)tile[tx][pl];
    }
}

// B,C slices -> (B,H,L,64) f16
__global__ __launch_bounds__(256) void make_BC(
    const float* __restrict__ zx, f16* __restrict__ Bc, f16* __restrict__ Cc)
{
    int i = blockIdx.x * 256 + threadIdx.x; // over B*L*H*64 = 1M
    int n = i & 63, h = (i >> 6) & 3, l = (i >> 8) & 2047, b = i >> 19;
    size_t rowoff = ((size_t)(b * 2048 + l)) * 4612 + 4100 + h * 128;
    size_t o = (((size_t)(b * 4 + h)) * 2048 + l) * 64 + n;
    Bc[o] = (f16)zx[rowoff + n];
    Cc[o] = (f16)zx[rowoff + 64 + n];
}

// ---------------------------------------------------------------------------
// Intra-chunk: per (c, bh) block.
//   S[t][s] = (s<=t) ? (C_t.B_s)*exp(cum_t-cum_s)*dt_s : 0
//   W[n][s] = B_s[n]*exp(cumEnd-cum_s)*dt_s
//   Y_intra = S @ X   (64x64 @ 64x512)
//   Hloc    = W @ X   (64x64 @ 64x512)
// ---------------------------------------------------------------------------
__global__ __launch_bounds__(256) void chunk_intra(
    const f16* __restrict__ Bc, const f16* __restrict__ Cc,
    const f16* __restrict__ xT,
    const float* __restrict__ dt, const float* __restrict__ cum,
    float* __restrict__ Y, float* __restrict__ Hloc)
{
    int c = blockIdx.x, bh = blockIdx.y;
    int l0 = c * 64;
    __shared__ f16 Cs[4096], Bs2[4096], Sb[4096], Wb[4096];
    __shared__ float cums[64], dts[64];
    int t = threadIdx.x;
    {
        const f16x8* sC = (const f16x8*)(Cc + ((size_t)bh * 2048 + l0) * 64);
        const f16x8* sB = (const f16x8*)(Bc + ((size_t)bh * 2048 + l0) * 64);
        ((f16x8*)Cs)[t] = sC[t];
        ((f16x8*)Cs)[t + 256] = sC[t + 256];
        ((f16x8*)Bs2)[t] = sB[t];
        ((f16x8*)Bs2)[t + 256] = sB[t + 256];
    }
    if (t < 64) {
        cums[t] = cum[bh * 2048 + l0 + t];
        dts[t] = dt[bh * 2048 + l0 + t];
    }
    __syncthreads();
    float cumEnd = cums[63];
    int lane = t & 63, w = t >> 6;
    int mrow = lane & 15, ksel = lane >> 4;

    // ---- S = tril(C @ B^T) * decay via MFMA; wave w owns rows w*16..w*16+15
    {
        f16x8 cf[2];
        cf[0] = *(const f16x8*)(Cs + (w * 16 + mrow) * 64 + ksel * 8);
        cf[1] = *(const f16x8*)(Cs + (w * 16 + mrow) * 64 + 32 + ksel * 8);
#pragma unroll
        for (int j = 0; j < 4; j++) {
            f32x4 d = {0.f, 0.f, 0.f, 0.f};
#pragma unroll
            for (int ks = 0; ks < 2; ks++) {
                f16x8 bfv = *(const f16x8*)(Bs2 + (j * 16 + mrow) * 64 + ks * 32 + ksel * 8);
                d = __builtin_amdgcn_mfma_f32_16x16x32_f16(cf[ks], bfv, d, 0, 0, 0);
            }
            int ss = j * 16 + mrow;
#pragma unroll
            for (int r = 0; r < 4; r++) {
                int tt = w * 16 + ksel * 4 + r;
                float sv = (ss <= tt) ? d[r] * __expf(cums[tt] - cums[ss]) * dts[ss] : 0.f;
                Sb[tt * 64 + ss] = (f16)sv;
            }
        }
#pragma unroll
        for (int q2 = 0; q2 < 16; q2++) {
            int idx = t * 16 + q2;
            int tt = idx >> 6, ss = idx & 63;
            float wv = (float)Bs2[ss * 64 + tt] * __expf(cumEnd - cums[ss]) * dts[ss];
            Wb[tt * 64 + ss] = (f16)wv;
        }
    }
    __syncthreads();

    f16x8 sfr[2][4], wfr[2][4];
#pragma unroll
    for (int ks = 0; ks < 2; ks++)
#pragma unroll
        for (int mt = 0; mt < 4; mt++) {
            sfr[ks][mt] = *(const f16x8*)(Sb + (mt * 16 + mrow) * 64 + ks * 32 + ksel * 8);
            wfr[ks][mt] = *(const f16x8*)(Wb + (mt * 16 + mrow) * 64 + ks * 32 + ksel * 8);
        }
    const f16* xbase = xT + ((size_t)bh * 512) * 2048 + c * 64;
    f32x4 zero = {0.f, 0.f, 0.f, 0.f};
#pragma unroll
    for (int ph = 0; ph < 2; ph++) {
        int pb = w * 128 + ph * 64;
        f32x4 aY[4][4], aH[4][4];
#pragma unroll
        for (int i = 0; i < 4; i++)
#pragma unroll
            for (int j = 0; j < 4; j++) { aY[i][j] = zero; aH[i][j] = zero; }
#pragma unroll
        for (int ks = 0; ks < 2; ks++) {
#pragma unroll
            for (int nt = 0; nt < 4; nt++) {
                int pp = pb + nt * 16 + mrow;
                f16x8 bfv = *(const f16x8*)(xbase + (size_t)pp * 2048 + ks * 32 + ksel * 8);
#pragma unroll
                for (int mt = 0; mt < 4; mt++) {
                    aY[mt][nt] = __builtin_amdgcn_mfma_f32_16x16x32_f16(sfr[ks][mt], bfv, aY[mt][nt], 0, 0, 0);
                    aH[mt][nt] = __builtin_amdgcn_mfma_f32_16x16x32_f16(wfr[ks][mt], bfv, aH[mt][nt], 0, 0, 0);
                }
            }
        }
        int r0 = ksel * 4;
#pragma unroll
        for (int mt = 0; mt < 4; mt++)
#pragma unroll
            for (int nt = 0; nt < 4; nt++) {
                int pp = pb + nt * 16 + mrow;
#pragma unroll
                for (int r = 0; r < 4; r++) {
                    int tt = mt * 16 + r0 + r;
                    Y[((size_t)bh * 2048 + l0 + tt) * 512 + pp] = aY[mt][nt][r];
                    Hloc[(((size_t)bh * 32 + c) * 64 + tt) * 512 + pp] = aH[mt][nt][r];
                }
            }
    }
}

// ---------------------------------------------------------------------------
// Cross-chunk recurrence. Thread owns (p, 4 n's) of one bh. Writes the state
// BEFORE chunk c as HpreT (BH,32,512,64) f16.
// ---------------------------------------------------------------------------
__global__ __launch_bounds__(256) void chunk_scan(
    const float* __restrict__ Hloc, const float* __restrict__ E,
    f16* __restrict__ HpreT)
{
    int bh = blockIdx.y;
    int p = blockIdx.x * 64 + (threadIdx.x & 63);
    int nb = blockIdx.z * 16 + (threadIdx.x >> 6) * 4;
    float h[4];
#pragma unroll
    for (int j = 0; j < 4; j++) h[j] = 0.f;
    float Eprev = 0.f;
    for (int c = 0; c < 32; c++) {
        size_t ob = (((size_t)bh * 32 + c) * 512 + p) * 64 + nb;
        f16x4 v;
#pragma unroll
        for (int j = 0; j < 4; j++) v[j] = (f16)h[j];
        *(f16x4*)(HpreT + ob) = v;
        float Ec = E[bh * 32 + c];
        float decay = __expf(Ec - Eprev);
        Eprev = Ec;
        size_t ib = (((size_t)bh * 32 + c) * 64 + nb) * 512 + p;
#pragma unroll
        for (int j = 0; j < 4; j++)
            h[j] = decay * h[j] + Hloc[ib + (size_t)j * 512];
    }
}

// ---------------------------------------------------------------------------
// Inter-chunk Y += Chat @ Hpre, then fused epilogue:
//   y = Y_intra + Y_inter + x*D; out = y * silu(z)  -> ybuf f16 (B*L, 2048)
// ---------------------------------------------------------------------------
__global__ __launch_bounds__(256) void chunk_inter(
    const f16* __restrict__ Cc, const f16* __restrict__ HpreT,
    const float* __restrict__ cum, const float* __restrict__ E,
    const float* __restrict__ Y, const float* __restrict__ zx,
    const float* __restrict__ Dp, f16* __restrict__ ybuf)
{
    int c = blockIdx.x, bh = blockIdx.y;
    int b = bh >> 2, h = bh & 3;
    int l0 = c * 64;
    __shared__ f16 Chat[4096];
    int t = threadIdx.x;
    float Eprev = (c > 0) ? E[bh * 32 + c - 1] : 0.f;
    for (int i = t; i < 4096; i += 256) {
        int tt = i >> 6, n = i & 63;
        float cv = (float)Cc[((size_t)bh * 2048 + l0 + tt) * 64 + n];
        Chat[i] = (f16)(cv * __expf(cum[bh * 2048 + l0 + tt] - Eprev));
    }
    __syncthreads();
    int lane = t & 63, w = t >> 6;
    int mrow = lane & 15, ksel = lane >> 4;
    float Dh = Dp[h];
    f16x8 af[2][4];
#pragma unroll
    for (int ks = 0; ks < 2; ks++)
#pragma unroll
        for (int mt = 0; mt < 4; mt++)
            af[ks][mt] = *(const f16x8*)(Chat + (mt * 16 + mrow) * 64 + ks * 32 + ksel * 8);
    const f16* hb = HpreT + (((size_t)bh * 32 + c) * 512) * 64;
    f32x4 zero = {0.f, 0.f, 0.f, 0.f};
#pragma unroll
    for (int ph = 0; ph < 2; ph++) {
        int pb = w * 128 + ph * 64;
        f32x4 acc[4][4];
#pragma unroll
        for (int i = 0; i < 4; i++)
#pragma unroll
            for (int j = 0; j < 4; j++) acc[i][j] = zero;
#pragma unroll
        for (int ks = 0; ks < 2; ks++) {
#pragma unroll
            for (int nt = 0; nt < 4; nt++) {
                int pp = pb + nt * 16 + mrow;
                f16x8 bfv = *(const f16x8*)(hb + (size_t)pp * 64 + ks * 32 + ksel * 8);
#pragma unroll
                for (int mt = 0; mt < 4; mt++)
                    acc[mt][nt] = __builtin_amdgcn_mfma_f32_16x16x32_f16(af[ks][mt], bfv, acc[mt][nt], 0, 0, 0);
            }
        }
        int r0 = ksel * 4;
#pragma unroll
        for (int mt = 0; mt < 4; mt++)
#pragma unroll
            for (int nt = 0; nt < 4; nt++) {
                int pp = pb + nt * 16 + mrow;
#pragma unroll
                for (int r = 0; r < 4; r++) {
                    int tt = mt * 16 + r0 + r;
                    int l = l0 + tt;
                    size_t zrow = ((size_t)(b * 2048 + l)) * 4612;
                    float y = acc[mt][nt][r] + Y[((size_t)bh * 2048 + l) * 512 + pp];
                    float x = zx[zrow + 2048 + h * 512 + pp];
                    y += x * Dh;
                    float z = zx[zrow + h * 512 + pp];
                    float sig = 1.f / (1.f + __expf(-z));
                    ybuf[((size_t)(b * 2048 + l)) * 2048 + h * 512 + pp] = (f16)(y * z * sig);
                }
            }
    }
}

// H_new[tok, s*256+j] = sum_i M[s][i]*H_old[tok, i*256+j] + xout[tok, s*256+j]
__global__ __launch_bounds__(256) void mix_add(
    const float* __restrict__ Hold, const float* __restrict__ xout,
    const float* __restrict__ Mm, float* __restrict__ Hnew)
{
    int i = blockIdx.x * 256 + threadIdx.x;
    int j = i & 255, tok = i >> 8;
    size_t rb = (size_t)tok * 1024;
    float h0 = Hold[rb + j], h1 = Hold[rb + 256 + j];
    float h2 = Hold[rb + 512 + j], h3 = Hold[rb + 768 + j];
#pragma unroll
    for (int s = 0; s < 4; s++) {
        float v = Mm[s*4+0]*h0 + Mm[s*4+1]*h1 + Mm[s*4+2]*h2 + Mm[s*4+3]*h3
                + xout[rb + s * 256 + j];
        Hnew[rb + s * 256 + j] = v;
    }
}

// ---------------------------------------------------------------------------
extern "C" void kernel_launch(void* const* d_in, const int* in_sizes, int n_in,
                              void* d_out, int out_size, void* d_ws, size_t ws_size,
                              hipStream_t stream)
{
    const int*   tokens     = (const int*)d_in[0];
    const float* embed      = (const float*)d_in[1];
    const float* norm_w     = (const float*)d_in[2];
    const float* in_proj_W  = (const float*)d_in[3];
    const float* in_proj_b  = (const float*)d_in[4];
    const float* A_log      = (const float*)d_in[5];
    const float* Dp         = (const float*)d_in[6];
    const float* dt_bias    = (const float*)d_in[7];
    const float* out_proj_W = (const float*)d_in[8];
    const float* out_proj_b = (const float*)d_in[9];
    const float* mixer_log  = (const float*)d_in[10];
    const float* norm_f_w   = (const float*)d_in[11];
    const float* head_W     = (const float*)d_in[12];
    const float* head_b     = (const float*)d_in[13];
    float* out = (float*)d_out;
    (void)in_sizes; (void)n_in; (void)out_size; (void)ws_size;

    char* base = (char*)d_ws;
    size_t off = 0;
    auto alloc = [&](size_t bytes) -> void* {
        void* r = (void*)(base + off);
        off = (off + bytes + 255) & ~(size_t)255;
        return r;
    };
    f16*   WinT   = (f16*)alloc(4ull * 4864 * 1024 * 2);   // Npad 4864 (19 x 256)
    f16*   WoutT  = (f16*)alloc(4ull * 1024 * 2048 * 2);
    f16*   WheadT = (f16*)alloc(32000ull * 1024 * 2);
    float* Mall   = (float*)alloc(64 * 4);
    float* H0     = (float*)alloc(4096ull * 1024 * 4);
    float* H1     = (float*)alloc(4096ull * 1024 * 4);
    f16*   un     = (f16*)alloc(4096ull * 1024 * 2);
    float* zx     = (float*)alloc(4096ull * 4612 * 4);
    float* dtb    = (float*)alloc(8ull * 2048 * 4);
    float* cumb   = (float*)alloc(8ull * 2048 * 4);
    float* Eb     = (float*)alloc(8ull * 32 * 4);
    f16*   xT     = (f16*)alloc(8ull * 512 * 2048 * 2);
    f16*   Bc     = (f16*)alloc(8ull * 2048 * 64 * 2);
    f16*   Cc     = (f16*)alloc(8ull * 2048 * 64 * 2);
    float* Yb     = (float*)alloc(8ull * 2048 * 512 * 4);
    float* Hloc   = (float*)alloc(8ull * 32 * 64 * 512 * 4);
    f16*   HpreT  = (f16*)alloc(8ull * 32 * 512 * 64 * 2);
    f16*   ybuf   = (f16*)alloc(4096ull * 2048 * 2);
    float* xout   = (float*)alloc(4096ull * 1024 * 4);

    // Weight conversion (every call; inputs are re-restored by harness)
    for (int l = 0; l < 4; l++) {
        transpose_w<<<dim3(152, 32), 256, 0, stream>>>(
            in_proj_W + (size_t)l * 1024 * 4612, WinT + (size_t)l * 4864 * 1024,
            1024, 4612, 4864);
        transpose_w<<<dim3(32, 64), 256, 0, stream>>>(
            out_proj_W + (size_t)l * 2048 * 1024, WoutT + (size_t)l * 1024 * 2048,
            2048, 1024, 1024);
    }
    transpose_w<<<dim3(1000, 32), 256, 0, stream>>>(head_W, WheadT, 1024, 32000, 32000);
    sinkhorn_k<<<1, 64, 0, stream>>>(mixer_log, Mall);
    embed_gather<<<4096, 256, 0, stream>>>(tokens, embed, H0);

    float* Hc = H0;
    float* Hn = H1;
    for (int l = 0; l < 4; l++) {
        rmsnorm_k<<<4096, 256, 0, stream>>>(Hc, norm_w + l * 1024, un);
        gemm256<<<dim3(16, 19), 512, 0, stream>>>(
            un, WinT + (size_t)l * 4864 * 1024, in_proj_b + l * 4612, zx,
            4096, 4612, 1024);
        dt_cumsum<<<8, 256, 0, stream>>>(zx, dt_bias + l * 4, A_log + l * 4, dtb, cumb, Eb);
        make_xT<<<dim3(32, 8, 8), 256, 0, stream>>>(zx, xT);
        make_BC<<<4096, 256, 0, stream>>>(zx, Bc, Cc);
        chunk_intra<<<dim3(32, 8), 256, 0, stream>>>(Bc, Cc, xT, dtb, cumb, Yb, Hloc);
        chunk_scan<<<dim3(8, 8, 4), 256, 0, stream>>>(Hloc, Eb, HpreT);
        chunk_inter<<<dim3(32, 8), 256, 0, stream>>>(Cc, HpreT, cumb, Eb, Yb, zx, Dp + l * 4, ybuf);
        gemm_f16<<<dim3(32, 8), 256, 0, stream>>>(
            ybuf, WoutT + (size_t)l * 1024 * 2048, out_proj_b + l * 1024, xout,
            4096, 1024, 2048);
        mix_add<<<4096, 256, 0, stream>>>(Hc, xout, Mall + l * 16, Hn);
        float* tmp = Hc; Hc = Hn; Hn = tmp;
    }
    rmsnorm_k<<<4096, 256, 0, stream>>>(Hc, norm_f_w, un);
    gemm256<<<dim3(16, 125), 512, 0, stream>>>(un, WheadT, head_b, out, 4096, 32000, 1024);
}

// Round 3
// 2076.625 us; speedup vs baseline: 1.0948x; 1.0111x over previous
//
#include <hip/hip_runtime.h>
#include <hip/hip_fp16.h>
#include <cstdint>

// ---------------------------------------------------------------------------
// Multi-stream Mamba2-ish LM forward on gfx950.
// All big matmuls: f16 MFMA (16x16x32), f32 accumulate.
// Scan: chunked SSD (chunk Q=64): intra-chunk matmuls + cross-chunk recurrence.
// ---------------------------------------------------------------------------

typedef _Float16 f16;
typedef __attribute__((ext_vector_type(8))) _Float16 f16x8;
typedef __attribute__((ext_vector_type(4))) _Float16 f16x4;
typedef __attribute__((ext_vector_type(4))) float f32x4;

#define LDS_CAST(p) ((__attribute__((address_space(3))) void*)(p))
#define GLB_CAST(p) ((const __attribute__((address_space(1))) void*)(p))

static __device__ __forceinline__ void gload16(const void* g, void* l) {
    __builtin_amdgcn_global_load_lds(GLB_CAST(g), LDS_CAST(l), 16, 0, 0);
}

// ---------------------------------------------------------------------------
// gemm256: C(MxN,f32) = A(MxK,f16) @ Bt(NxK,f16)^T + bias
// 256x256 tile, BK=32, 512 threads (8 waves, 2M x 4N), per-wave 128x64 out.
// T3+T4: triple-buffered LDS ring, stage 2 K-tiles ahead, 2 phases per K-tile,
// raw s_barrier (no vmcnt(0) drain), one counted s_waitcnt vmcnt(4) per tile.
// T2 (corrected r3): bank = 16*(row&1) + 4*chunk; chunk = ksel ^ ((row>>1)&3)
// puts each 16-lane fragment-read group on all 8 four-bank groups, 2-way=free.
// (Round-2's ksel^(row&3) only reached 4-way: bit0 of row aliased with the
// 16*(row&1) term.) Global source pre-swizzled, LDS dest linear (rule 21).
// T5: setprio(1) around each 16-MFMA cluster.
// Requires: M%256==0, Npad%256==0 (zero-padded Bt rows), K%32==0, K>=96.
// ---------------------------------------------------------------------------
__global__ __launch_bounds__(512, 2) void gemm256(
    const f16* __restrict__ A, const f16* __restrict__ Bt,
    const float* __restrict__ bias, float* __restrict__ C,
    int M, int N, int K)
{
    __shared__ f16 AS[3 * 256 * 32];   // 3 slots x (256 rows x 32 f16) = 48KB
    __shared__ f16 BS[3 * 256 * 32];   // 48KB

    const int tid = threadIdx.x;
    const int lane = tid & 63;
    const int w = tid >> 6;
    const int wr = w >> 2;            // 0..1  (M half)
    const int wc = w & 3;             // 0..3  (N quarter)
    const int mrow = lane & 15, ksel = lane >> 4;

    // ---- tile-order swizzle (m204 bijective XCD chunk + GROUP_M=8 m-fast) ---
    const int gx = gridDim.x;         // M tiles
    const int gy = gridDim.y;         // N tiles
    const int nwg = gx * gy;
    int lin = blockIdx.y * gx + blockIdx.x;
    int xcd = lin & 7, loc = lin >> 3;
    int q = nwg >> 3, rr = nwg & 7;
    int wg = (xcd < rr) ? (xcd * (q + 1) + loc)
                        : (rr * (q + 1) + (xcd - rr) * q + loc);
    const int GROUP = 8;
    int per_group = GROUP * gy;
    int gid = wg / per_group;
    int first_m = gid * GROUP;
    int gsz = (gx - first_m < GROUP) ? (gx - first_m) : GROUP;
    int inner = wg - gid * per_group;
    const int m0 = (first_m + inner % gsz) * 256;
    const int n0 = (inner / gsz) * 256;
    // ------------------------------------------------------------------------

    // staging geometry: half-tile = 128 rows x 32 f16 (8KB), 1 gload16/thread.
    // physical LDS cell (row, 16B-chunk c) holds logical chunk c ^ ((row>>1)&3).
    const int rowt = tid >> 2;                             // 0..127
    const int colE = ((tid & 3) ^ ((rowt >> 1) & 3)) * 8;  // pre-swizzled source col
    const int ldst = tid * 8;                              // linear LDS dest (elems)

    const f16* gA = A + (size_t)m0 * K;
    const f16* gB = Bt + (size_t)n0 * K;
    const size_t gofsA0 = (size_t)rowt * K + colE;
    const size_t gofsA1 = (size_t)(128 + rowt) * K + colE;   // +128 keeps row bits 1-2
    const size_t gofsB0 = gofsA0;
    const size_t gofsB1 = gofsA1;

    // fragment read offsets (swizzled): row*32 + (ksel ^ ((row>>1)&3))*8;
    // row bits 1-2 come from mrow only (mf*16, wr*128 are 16-aligned).
    const int fcol = ((ksel ^ ((mrow >> 1) & 3)) * 8);
    int offA[8], offB[4];
#pragma unroll
    for (int mf = 0; mf < 8; mf++)
        offA[mf] = (wr * 128 + mf * 16 + mrow) * 32 + fcol;
#pragma unroll
    for (int nf = 0; nf < 4; nf++)
        offB[nf] = (wc * 64 + nf * 16 + mrow) * 32 + fcol;

    f32x4 zero = {0.f, 0.f, 0.f, 0.f};
    f32x4 acc[8][4];
#pragma unroll
    for (int i = 0; i < 8; i++)
#pragma unroll
        for (int j = 0; j < 4; j++) acc[i][j] = zero;

    const int nt = K >> 5;

    // ---- prologue: stage tiles 0 and 1 into slots 0,1 -----------------------
#pragma unroll
    for (int T = 0; T < 2; ++T) {
        gload16(gA + gofsA0 + (size_t)T * 32, AS + T * 8192 + ldst);
        gload16(gA + gofsA1 + (size_t)T * 32, AS + T * 8192 + 4096 + ldst);
        gload16(gB + gofsB0 + (size_t)T * 32, BS + T * 8192 + ldst);
        gload16(gB + gofsB1 + (size_t)T * 32, BS + T * 8192 + 4096 + ldst);
    }
    asm volatile("s_waitcnt vmcnt(4)" ::: "memory");  // tile 0 resident
    __builtin_amdgcn_sched_barrier(0);
    __builtin_amdgcn_s_barrier();

    // ---- main loop ----------------------------------------------------------
    for (int t = 0; t < nt; ++t) {
        const int slot = t % 3;
        const f16* as = AS + slot * 8192;
        const f16* bs = BS + slot * 8192;
        const int sst = (t + 2) % 3;
        const bool st = (t + 2) < nt;
        const size_t kof = (size_t)(t + 2) * 32;

        // ---- phase 0: read af[0..3] + bf[0..3]; stage A halves of t+2 -------
        f16x8 af[4], bf[4];
#pragma unroll
        for (int mf = 0; mf < 4; mf++) af[mf] = *(const f16x8*)(as + offA[mf]);
#pragma unroll
        for (int nf = 0; nf < 4; nf++) bf[nf] = *(const f16x8*)(bs + offB[nf]);
        if (st) {
            gload16(gA + gofsA0 + kof, AS + sst * 8192 + ldst);
            gload16(gA + gofsA1 + kof, AS + sst * 8192 + 4096 + ldst);
        }
        __builtin_amdgcn_s_barrier();
        __builtin_amdgcn_s_setprio(1);
#pragma unroll
        for (int mf = 0; mf < 4; mf++)
#pragma unroll
            for (int nf = 0; nf < 4; nf++)
                acc[mf][nf] = __builtin_amdgcn_mfma_f32_16x16x32_f16(bf[nf], af[mf], acc[mf][nf], 0, 0, 0);
        __builtin_amdgcn_s_setprio(0);
        __builtin_amdgcn_s_barrier();

        // ---- phase 1: read af[4..7]; stage B halves of t+2 ------------------
        f16x8 af2[4];
#pragma unroll
        for (int mf = 0; mf < 4; mf++) af2[mf] = *(const f16x8*)(as + offA[4 + mf]);
        if (st) {
            gload16(gB + gofsB0 + kof, BS + sst * 8192 + ldst);
            gload16(gB + gofsB1 + kof, BS + sst * 8192 + 4096 + ldst);
        }
        __builtin_amdgcn_s_barrier();
        __builtin_amdgcn_s_setprio(1);
#pragma unroll
        for (int mf = 0; mf < 4; mf++)
#pragma unroll
            for (int nf = 0; nf < 4; nf++)
                acc[4 + mf][nf] = __builtin_amdgcn_mfma_f32_16x16x32_f16(bf[nf], af2[mf], acc[4 + mf][nf], 0, 0, 0);
        __builtin_amdgcn_s_setprio(0);

        // ---- K-tile boundary: counted drain (never 0 in steady state) -------
        if (t + 1 < nt) {
            if (st) {
                asm volatile("s_waitcnt vmcnt(4)" ::: "memory");
            } else {
                asm volatile("s_waitcnt vmcnt(0)" ::: "memory");
            }
            __builtin_amdgcn_sched_barrier(0);
            __builtin_amdgcn_s_barrier();
        }
    }

    // ---- epilogue: float4 stores (acc regs walk 4 consecutive n) ------------
#pragma unroll
    for (int mf = 0; mf < 8; mf++) {
        int m = m0 + wr * 128 + mf * 16 + mrow;
#pragma unroll
        for (int nf = 0; nf < 4; nf++) {
            int nb = n0 + wc * 64 + nf * 16 + ksel * 4;
            if (nb < N) {
                float4 bv = {0.f, 0.f, 0.f, 0.f};
                if (bias) bv = *(const float4*)(bias + nb);
                float4 v;
                v.x = acc[mf][nf][0] + bv.x;
                v.y = acc[mf][nf][1] + bv.y;
                v.z = acc[mf][nf][2] + bv.z;
                v.w = acc[mf][nf][3] + bv.w;
                *(float4*)(C + (size_t)m * N + nb) = v;
            }
        }
    }
}

// ---------------------------------------------------------------------------
// Generic f16 GEMM (128x128 tile, m97 structure) — kept for out-proj (N=1024).
// ---------------------------------------------------------------------------
__global__ __launch_bounds__(256) void gemm_f16(
    const f16* __restrict__ A, const f16* __restrict__ Bt,
    const float* __restrict__ bias, float* __restrict__ C,
    int M, int N, int K)
{
    __shared__ f16 As[128 * 32];
    __shared__ f16 Bs[128 * 32];
    const int t = threadIdx.x;
    const int lane = t & 63;
    const int w = t >> 6;

    const int gx = gridDim.x;            // M tiles
    const int gy = gridDim.y;            // N tiles
    const int nwg = gx * gy;
    int lin = blockIdx.y * gx + blockIdx.x;
    int xcd = lin & 7, loc = lin >> 3;
    int q = nwg >> 3, rr = nwg & 7;
    int wg = (xcd < rr) ? (xcd * (q + 1) + loc)
                        : (rr * (q + 1) + (xcd - rr) * q + loc);
    const int GROUP = 8;
    int per_group = GROUP * gy;
    int gid = wg / per_group;
    int first_m = gid * GROUP;
    int gsz = (gx - first_m < GROUP) ? (gx - first_m) : GROUP;
    int inner = wg - gid * per_group;
    const int m0 = (first_m + inner % gsz) * 128;
    const int n0 = (inner / gsz) * 128;

    const int wm0 = (w >> 1) * 64, wn0 = (w & 1) * 64;
    const int mrow = lane & 15, ksel = lane >> 4;

    f32x4 zero = {0.f, 0.f, 0.f, 0.f};
    f32x4 acc[4][4];
#pragma unroll
    for (int i = 0; i < 4; i++)
#pragma unroll
        for (int j = 0; j < 4; j++) acc[i][j] = zero;

    const f16* Abase = A + (size_t)m0 * K;
    const f16* Bbase = Bt + (size_t)n0 * K;

    for (int k0 = 0; k0 < K; k0 += 32) {
#pragma unroll
        for (int i = 0; i < 2; i++) {
            int lin2 = t + i * 256;
            int r = lin2 >> 2;
            int cc = (lin2 & 3) * 8;
            gload16(Abase + (size_t)r * K + k0 + cc, As + lin2 * 8);
            gload16(Bbase + (size_t)r * K + k0 + cc, Bs + lin2 * 8);
        }
        __syncthreads();
        f16x8 af[4], bf[4];
#pragma unroll
        for (int i = 0; i < 4; i++) {
            af[i] = *(const f16x8*)(As + (wm0 + i * 16 + mrow) * 32 + ksel * 8);
            bf[i] = *(const f16x8*)(Bs + (wn0 + i * 16 + mrow) * 32 + ksel * 8);
        }
#pragma unroll
        for (int i = 0; i < 4; i++)
#pragma unroll
            for (int j = 0; j < 4; j++)
                acc[i][j] = __builtin_amdgcn_mfma_f32_16x16x32_f16(bf[j], af[i], acc[i][j], 0, 0, 0);
        __syncthreads();
    }

#pragma unroll
    for (int i = 0; i < 4; i++) {
        int m = m0 + wm0 + i * 16 + mrow;
#pragma unroll
        for (int j = 0; j < 4; j++) {
            int nb = n0 + wn0 + j * 16 + ksel * 4;
            if (nb < N) {
                float4 bv = {0.f, 0.f, 0.f, 0.f};
                if (bias) bv = *(const float4*)(bias + nb);
                float4 v;
                v.x = acc[i][j][0] + bv.x;
                v.y = acc[i][j][1] + bv.y;
                v.z = acc[i][j][2] + bv.z;
                v.w = acc[i][j][3] + bv.w;
                *(float4*)(C + (size_t)m * N + nb) = v;
            }
        }
    }
}

// ---------------------------------------------------------------------------
// Weight convert+transpose: W(KxN,f32) -> Wt(NpadxK,f16), zero-filled pad rows.
// ---------------------------------------------------------------------------
__global__ __launch_bounds__(256) void transpose_w(
    const float* __restrict__ W, f16* __restrict__ Wt, int K, int N, int Npad)
{
    __shared__ float tile[32][33];
    int n0 = blockIdx.x * 32, k0 = blockIdx.y * 32;
    int tx = threadIdx.x & 31, ty = threadIdx.x >> 5;
#pragma unroll
    for (int i = 0; i < 4; i++) {
        int k = k0 + ty + 8 * i;
        int n = n0 + tx;
        tile[ty + 8 * i][tx] = (n < N) ? W[(size_t)k * N + n] : 0.f;
    }
    __syncthreads();
#pragma unroll
    for (int i = 0; i < 4; i++) {
        int n = n0 + ty + 8 * i;
        if (n < Npad) Wt[(size_t)n * K + k0 + tx] = (f16)tile[tx][ty + 8 * i];
    }
}

// ---------------------------------------------------------------------------
// Sinkhorn on 4x4 mixer logits, all 4 layers; single thread (trivial work).
// ---------------------------------------------------------------------------
__global__ void sinkhorn_k(const float* __restrict__ logits, float* __restrict__ Mout)
{
    if (threadIdx.x != 0 || blockIdx.x != 0) return;
    for (int l = 0; l < 4; l++) {
        float M[16];
        for (int i = 0; i < 16; i++) {
            float v = logits[l * 16 + i];
            M[i] = 1.f / (1.f + __expf(-v)) + ((i % 5) == 0 ? 1.f : 0.f);
        }
        for (int it = 0; it < 5; it++) {
            for (int r = 0; r < 4; r++) {
                float s = M[r*4] + M[r*4+1] + M[r*4+2] + M[r*4+3] + 1e-6f;
                for (int c = 0; c < 4; c++) M[r*4+c] /= s;
            }
            for (int c = 0; c < 4; c++) {
                float s = M[c] + M[4+c] + M[8+c] + M[12+c] + 1e-6f;
                for (int r = 0; r < 4; r++) M[r*4+c] /= s;
            }
        }
        for (int i = 0; i < 16; i++) Mout[l * 16 + i] = M[i];
    }
}

__global__ __launch_bounds__(256) void embed_gather(
    const int* __restrict__ tokens, const float* __restrict__ embed, float* __restrict__ H)
{
    int i = blockIdx.x * 256 + threadIdx.x;
    int tok = i >> 8, d4 = i & 255;
    int tk = tokens[tok];
    float4 v = ((const float4*)(embed + (size_t)tk * 1024))[d4];
    ((float4*)(H + (size_t)tok * 1024))[d4] = v;
}

// RMSNorm over d=1024, one block per token, f16 output for GEMM A-operand.
__global__ __launch_bounds__(256) void rmsnorm_k(
    const float* __restrict__ X, const float* __restrict__ w, f16* __restrict__ out)
{
    int tok = blockIdx.x;
    int t = threadIdx.x;
    const float4 v = ((const float4*)(X + (size_t)tok * 1024))[t];
    float ss = v.x*v.x + v.y*v.y + v.z*v.z + v.w*v.w;
#pragma unroll
    for (int off = 32; off > 0; off >>= 1) ss += __shfl_down(ss, off, 64);
    __shared__ float wsum[4];
    if ((t & 63) == 0) wsum[t >> 6] = ss;
    __syncthreads();
    float tot = wsum[0] + wsum[1] + wsum[2] + wsum[3];
    float sc = rsqrtf(tot * (1.f / 1024.f) + 1.1920929e-07f);
    const float4 wv = ((const float4*)w)[t];
    f16x4 o;
    o[0] = (f16)(v.x * sc * wv.x);
    o[1] = (f16)(v.y * sc * wv.y);
    o[2] = (f16)(v.z * sc * wv.z);
    o[3] = (f16)(v.w * sc * wv.w);
    ((f16x4*)(out + (size_t)tok * 1024))[t] = o;
}

// ---------------------------------------------------------------------------
// dt = softplus(dt_raw + bias); cum = inclusive prefix of dt*A per (b,h);
// E[c] = cum at chunk ends. One block per (b,h).
// ---------------------------------------------------------------------------
__global__ __launch_bounds__(256) void dt_cumsum(
    const float* __restrict__ zx, const float* __restrict__ dt_bias,
    const float* __restrict__ A_log,
    float* __restrict__ dt, float* __restrict__ cum, float* __restrict__ E)
{
    int bh = blockIdx.x;
    int b = bh >> 2, h = bh & 3;
    int t = threadIdx.x;
    float Ah = -__expf(A_log[h]);
    float bias = dt_bias[h];
    float run = 0.f, vals[8];
    for (int i = 0; i < 8; i++) {
        int l = t * 8 + i;
        float raw = zx[((size_t)(b * 2048 + l)) * 4612 + 4096 + h] + bias;
        float dtv = (raw > 20.f) ? raw : log1pf(__expf(raw));
        dt[bh * 2048 + l] = dtv;
        run += dtv * Ah;
        vals[i] = run;
    }
    __shared__ float ps[256];
    ps[t] = run;
    __syncthreads();
    for (int off = 1; off < 256; off <<= 1) {
        float v = (t >= off) ? ps[t - off] : 0.f;
        __syncthreads();
        ps[t] += v;
        __syncthreads();
    }
    float offset = (t > 0) ? ps[t - 1] : 0.f;
    for (int i = 0; i < 8; i++) {
        int l = t * 8 + i;
        float cv = vals[i] + offset;
        cum[bh * 2048 + l] = cv;
        if ((l & 63) == 63) E[bh * 32 + (l >> 6)] = cv;
    }
}

// x slice of zxbcdt (f32) -> xT (B,H,P,L) f16 (transposed, L-contiguous)
__global__ __launch_bounds__(256) void make_xT(
    const float* __restrict__ zx, f16* __restrict__ xT)
{
    int lb = blockIdx.x * 64, pb = blockIdx.y * 64, bh = blockIdx.z;
    int b = bh >> 2, h = bh & 3;
    __shared__ float tile[64][65];
    int tx = threadIdx.x & 63, ty = threadIdx.x >> 6; // 64 x 4
#pragma unroll
    for (int i = 0; i < 16; i++) {
        int ll = ty + 4 * i;
        tile[ll][tx] = zx[((size_t)(b * 2048 + lb + ll)) * 4612 + 2048 + h * 512 + pb + tx];
    }
    __syncthreads();
#pragma unroll
    for (int i = 0; i < 16; i++) {
        int pl = ty + 4 * i;
        xT[((size_t)bh * 512 + pb + pl) * 2048 + lb + tx] = (f16)tile[tx][pl];
    }
}

// B,C slices -> (B,H,L,64) f16
__global__ __launch_bounds__(256) void make_BC(
    const float* __restrict__ zx, f16* __restrict__ Bc, f16* __restrict__ Cc)
{
    int i = blockIdx.x * 256 + threadIdx.x; // over B*L*H*64 = 1M
    int n = i & 63, h = (i >> 6) & 3, l = (i >> 8) & 2047, b = i >> 19;
    size_t rowoff = ((size_t)(b * 2048 + l)) * 4612 + 4100 + h * 128;
    size_t o = (((size_t)(b * 4 + h)) * 2048 + l) * 64 + n;
    Bc[o] = (f16)zx[rowoff + n];
    Cc[o] = (f16)zx[rowoff + 64 + n];
}

// ---------------------------------------------------------------------------
// Intra-chunk: per (c, bh) block.
//   S[t][s] = (s<=t) ? (C_t.B_s)*exp(cum_t-cum_s)*dt_s : 0
//   W[n][s] = B_s[n]*exp(cumEnd-cum_s)*dt_s
//   Y_intra = S @ X   (64x64 @ 64x512)
//   Hloc    = W @ X   (64x64 @ 64x512)
// ---------------------------------------------------------------------------
__global__ __launch_bounds__(256) void chunk_intra(
    const f16* __restrict__ Bc, const f16* __restrict__ Cc,
    const f16* __restrict__ xT,
    const float* __restrict__ dt, const float* __restrict__ cum,
    float* __restrict__ Y, float* __restrict__ Hloc)
{
    int c = blockIdx.x, bh = blockIdx.y;
    int l0 = c * 64;
    __shared__ f16 Cs[4096], Bs2[4096], Sb[4096], Wb[4096];
    __shared__ float cums[64], dts[64];
    int t = threadIdx.x;
    {
        const f16x8* sC = (const f16x8*)(Cc + ((size_t)bh * 2048 + l0) * 64);
        const f16x8* sB = (const f16x8*)(Bc + ((size_t)bh * 2048 + l0) * 64);
        ((f16x8*)Cs)[t] = sC[t];
        ((f16x8*)Cs)[t + 256] = sC[t + 256];
        ((f16x8*)Bs2)[t] = sB[t];
        ((f16x8*)Bs2)[t + 256] = sB[t + 256];
    }
    if (t < 64) {
        cums[t] = cum[bh * 2048 + l0 + t];
        dts[t] = dt[bh * 2048 + l0 + t];
    }
    __syncthreads();
    float cumEnd = cums[63];
    int lane = t & 63, w = t >> 6;
    int mrow = lane & 15, ksel = lane >> 4;

    // ---- S = tril(C @ B^T) * decay via MFMA; wave w owns rows w*16..w*16+15
    {
        f16x8 cf[2];
        cf[0] = *(const f16x8*)(Cs + (w * 16 + mrow) * 64 + ksel * 8);
        cf[1] = *(const f16x8*)(Cs + (w * 16 + mrow) * 64 + 32 + ksel * 8);
#pragma unroll
        for (int j = 0; j < 4; j++) {
            f32x4 d = {0.f, 0.f, 0.f, 0.f};
#pragma unroll
            for (int ks = 0; ks < 2; ks++) {
                f16x8 bfv = *(const f16x8*)(Bs2 + (j * 16 + mrow) * 64 + ks * 32 + ksel * 8);
                d = __builtin_amdgcn_mfma_f32_16x16x32_f16(cf[ks], bfv, d, 0, 0, 0);
            }
            int ss = j * 16 + mrow;
#pragma unroll
            for (int r = 0; r < 4; r++) {
                int tt = w * 16 + ksel * 4 + r;
                float sv = (ss <= tt) ? d[r] * __expf(cums[tt] - cums[ss]) * dts[ss] : 0.f;
                Sb[tt * 64 + ss] = (f16)sv;
            }
        }
#pragma unroll
        for (int q2 = 0; q2 < 16; q2++) {
            int idx = t * 16 + q2;
            int tt = idx >> 6, ss = idx & 63;
            float wv = (float)Bs2[ss * 64 + tt] * __expf(cumEnd - cums[ss]) * dts[ss];
            Wb[tt * 64 + ss] = (f16)wv;
        }
    }
    __syncthreads();

    f16x8 sfr[2][4], wfr[2][4];
#pragma unroll
    for (int ks = 0; ks < 2; ks++)
#pragma unroll
        for (int mt = 0; mt < 4; mt++) {
            sfr[ks][mt] = *(const f16x8*)(Sb + (mt * 16 + mrow) * 64 + ks * 32 + ksel * 8);
            wfr[ks][mt] = *(const f16x8*)(Wb + (mt * 16 + mrow) * 64 + ks * 32 + ksel * 8);
        }
    const f16* xbase = xT + ((size_t)bh * 512) * 2048 + c * 64;
    f32x4 zero = {0.f, 0.f, 0.f, 0.f};
#pragma unroll
    for (int ph = 0; ph < 2; ph++) {
        int pb = w * 128 + ph * 64;
        f32x4 aY[4][4], aH[4][4];
#pragma unroll
        for (int i = 0; i < 4; i++)
#pragma unroll
            for (int j = 0; j < 4; j++) { aY[i][j] = zero; aH[i][j] = zero; }
#pragma unroll
        for (int ks = 0; ks < 2; ks++) {
#pragma unroll
            for (int nt = 0; nt < 4; nt++) {
                int pp = pb + nt * 16 + mrow;
                f16x8 bfv = *(const f16x8*)(xbase + (size_t)pp * 2048 + ks * 32 + ksel * 8);
#pragma unroll
                for (int mt = 0; mt < 4; mt++) {
                    aY[mt][nt] = __builtin_amdgcn_mfma_f32_16x16x32_f16(sfr[ks][mt], bfv, aY[mt][nt], 0, 0, 0);
                    aH[mt][nt] = __builtin_amdgcn_mfma_f32_16x16x32_f16(wfr[ks][mt], bfv, aH[mt][nt], 0, 0, 0);
                }
            }
        }
        int r0 = ksel * 4;
#pragma unroll
        for (int mt = 0; mt < 4; mt++)
#pragma unroll
            for (int nt = 0; nt < 4; nt++) {
                int pp = pb + nt * 16 + mrow;
#pragma unroll
                for (int r = 0; r < 4; r++) {
                    int tt = mt * 16 + r0 + r;
                    Y[((size_t)bh * 2048 + l0 + tt) * 512 + pp] = aY[mt][nt][r];
                    Hloc[(((size_t)bh * 32 + c) * 64 + tt) * 512 + pp] = aH[mt][nt][r];
                }
            }
    }
}

// ---------------------------------------------------------------------------
// Cross-chunk recurrence. Thread owns (p, 4 n's) of one bh. Writes the state
// BEFORE chunk c as HpreT (BH,32,512,64) f16.
// ---------------------------------------------------------------------------
__global__ __launch_bounds__(256) void chunk_scan(
    const float* __restrict__ Hloc, const float* __restrict__ E,
    f16* __restrict__ HpreT)
{
    int bh = blockIdx.y;
    int p = blockIdx.x * 64 + (threadIdx.x & 63);
    int nb = blockIdx.z * 16 + (threadIdx.x >> 6) * 4;
    float h[4];
#pragma unroll
    for (int j = 0; j < 4; j++) h[j] = 0.f;
    float Eprev = 0.f;
    for (int c = 0; c < 32; c++) {
        size_t ob = (((size_t)bh * 32 + c) * 512 + p) * 64 + nb;
        f16x4 v;
#pragma unroll
        for (int j = 0; j < 4; j++) v[j] = (f16)h[j];
        *(f16x4*)(HpreT + ob) = v;
        float Ec = E[bh * 32 + c];
        float decay = __expf(Ec - Eprev);
        Eprev = Ec;
        size_t ib = (((size_t)bh * 32 + c) * 64 + nb) * 512 + p;
#pragma unroll
        for (int j = 0; j < 4; j++)
            h[j] = decay * h[j] + Hloc[ib + (size_t)j * 512];
    }
}

// ---------------------------------------------------------------------------
// Inter-chunk Y += Chat @ Hpre, then fused epilogue:
//   y = Y_intra + Y_inter + x*D; out = y * silu(z)  -> ybuf f16 (B*L, 2048)
// ---------------------------------------------------------------------------
__global__ __launch_bounds__(256) void chunk_inter(
    const f16* __restrict__ Cc, const f16* __restrict__ HpreT,
    const float* __restrict__ cum, const float* __restrict__ E,
    const float* __restrict__ Y, const float* __restrict__ zx,
    const float* __restrict__ Dp, f16* __restrict__ ybuf)
{
    int c = blockIdx.x, bh = blockIdx.y;
    int b = bh >> 2, h = bh & 3;
    int l0 = c * 64;
    __shared__ f16 Chat[4096];
    int t = threadIdx.x;
    float Eprev = (c > 0) ? E[bh * 32 + c - 1] : 0.f;
    for (int i = t; i < 4096; i += 256) {
        int tt = i >> 6, n = i & 63;
        float cv = (float)Cc[((size_t)bh * 2048 + l0 + tt) * 64 + n];
        Chat[i] = (f16)(cv * __expf(cum[bh * 2048 + l0 + tt] - Eprev));
    }
    __syncthreads();
    int lane = t & 63, w = t >> 6;
    int mrow = lane & 15, ksel = lane >> 4;
    float Dh = Dp[h];
    f16x8 af[2][4];
#pragma unroll
    for (int ks = 0; ks < 2; ks++)
#pragma unroll
        for (int mt = 0; mt < 4; mt++)
            af[ks][mt] = *(const f16x8*)(Chat + (mt * 16 + mrow) * 64 + ks * 32 + ksel * 8);
    const f16* hb = HpreT + (((size_t)bh * 32 + c) * 512) * 64;
    f32x4 zero = {0.f, 0.f, 0.f, 0.f};
#pragma unroll
    for (int ph = 0; ph < 2; ph++) {
        int pb = w * 128 + ph * 64;
        f32x4 acc[4][4];
#pragma unroll
        for (int i = 0; i < 4; i++)
#pragma unroll
            for (int j = 0; j < 4; j++) acc[i][j] = zero;
#pragma unroll
        for (int ks = 0; ks < 2; ks++) {
#pragma unroll
            for (int nt = 0; nt < 4; nt++) {
                int pp = pb + nt * 16 + mrow;
                f16x8 bfv = *(const f16x8*)(hb + (size_t)pp * 64 + ks * 32 + ksel * 8);
#pragma unroll
                for (int mt = 0; mt < 4; mt++)
                    acc[mt][nt] = __builtin_amdgcn_mfma_f32_16x16x32_f16(af[ks][mt], bfv, acc[mt][nt], 0, 0, 0);
            }
        }
        int r0 = ksel * 4;
#pragma unroll
        for (int mt = 0; mt < 4; mt++)
#pragma unroll
            for (int nt = 0; nt < 4; nt++) {
                int pp = pb + nt * 16 + mrow;
#pragma unroll
                for (int r = 0; r < 4; r++) {
                    int tt = mt * 16 + r0 + r;
                    int l = l0 + tt;
                    size_t zrow = ((size_t)(b * 2048 + l)) * 4612;
                    float y = acc[mt][nt][r] + Y[((size_t)bh * 2048 + l) * 512 + pp];
                    float x = zx[zrow + 2048 + h * 512 + pp];
                    y += x * Dh;
                    float z = zx[zrow + h * 512 + pp];
                    float sig = 1.f / (1.f + __expf(-z));
                    ybuf[((size_t)(b * 2048 + l)) * 2048 + h * 512 + pp] = (f16)(y * z * sig);
                }
            }
    }
}

// H_new[tok, s*256+j] = sum_i M[s][i]*H_old[tok, i*256+j] + xout[tok, s*256+j]
__global__ __launch_bounds__(256) void mix_add(
    const float* __restrict__ Hold, const float* __restrict__ xout,
    const float* __restrict__ Mm, float* __restrict__ Hnew)
{
    int i = blockIdx.x * 256 + threadIdx.x;
    int j = i & 255, tok = i >> 8;
    size_t rb = (size_t)tok * 1024;
    float h0 = Hold[rb + j], h1 = Hold[rb + 256 + j];
    float h2 = Hold[rb + 512 + j], h3 = Hold[rb + 768 + j];
#pragma unroll
    for (int s = 0; s < 4; s++) {
        float v = Mm[s*4+0]*h0 + Mm[s*4+1]*h1 + Mm[s*4+2]*h2 + Mm[s*4+3]*h3
                + xout[rb + s * 256 + j];
        Hnew[rb + s * 256 + j] = v;
    }
}

// ---------------------------------------------------------------------------
extern "C" void kernel_launch(void* const* d_in, const int* in_sizes, int n_in,
                              void* d_out, int out_size, void* d_ws, size_t ws_size,
                              hipStream_t stream)
{
    const int*   tokens     = (const int*)d_in[0];
    const float* embed      = (const float*)d_in[1];
    const float* norm_w     = (const float*)d_in[2];
    const float* in_proj_W  = (const float*)d_in[3];
    const float* in_proj_b  = (const float*)d_in[4];
    const float* A_log      = (const float*)d_in[5];
    const float* Dp         = (const float*)d_in[6];
    const float* dt_bias    = (const float*)d_in[7];
    const float* out_proj_W = (const float*)d_in[8];
    const float* out_proj_b = (const float*)d_in[9];
    const float* mixer_log  = (const float*)d_in[10];
    const float* norm_f_w   = (const float*)d_in[11];
    const float* head_W     = (const float*)d_in[12];
    const float* head_b     = (const float*)d_in[13];
    float* out = (float*)d_out;
    (void)in_sizes; (void)n_in; (void)out_size; (void)ws_size;

    char* base = (char*)d_ws;
    size_t off = 0;
    auto alloc = [&](size_t bytes) -> void* {
        void* r = (void*)(base + off);
        off = (off + bytes + 255) & ~(size_t)255;
        return r;
    };
    f16*   WinT   = (f16*)alloc(4ull * 4864 * 1024 * 2);   // Npad 4864 (19 x 256)
    f16*   WoutT  = (f16*)alloc(4ull * 1024 * 2048 * 2);
    f16*   WheadT = (f16*)alloc(32000ull * 1024 * 2);
    float* Mall   = (float*)alloc(64 * 4);
    float* H0     = (float*)alloc(4096ull * 1024 * 4);
    float* H1     = (float*)alloc(4096ull * 1024 * 4);
    f16*   un     = (f16*)alloc(4096ull * 1024 * 2);
    float* zx     = (float*)alloc(4096ull * 4612 * 4);
    float* dtb    = (float*)alloc(8ull * 2048 * 4);
    float* cumb   = (float*)alloc(8ull * 2048 * 4);
    float* Eb     = (float*)alloc(8ull * 32 * 4);
    f16*   xT     = (f16*)alloc(8ull * 512 * 2048 * 2);
    f16*   Bc     = (f16*)alloc(8ull * 2048 * 64 * 2);
    f16*   Cc     = (f16*)alloc(8ull * 2048 * 64 * 2);
    float* Yb     = (float*)alloc(8ull * 2048 * 512 * 4);
    float* Hloc   = (float*)alloc(8ull * 32 * 64 * 512 * 4);
    f16*   HpreT  = (f16*)alloc(8ull * 32 * 512 * 64 * 2);
    f16*   ybuf   = (f16*)alloc(4096ull * 2048 * 2);
    float* xout   = (float*)alloc(4096ull * 1024 * 4);

    // Weight conversion (every call; inputs are re-restored by harness)
    for (int l = 0; l < 4; l++) {
        transpose_w<<<dim3(152, 32), 256, 0, stream>>>(
            in_proj_W + (size_t)l * 1024 * 4612, WinT + (size_t)l * 4864 * 1024,
            1024, 4612, 4864);
        transpose_w<<<dim3(32, 64), 256, 0, stream>>>(
            out_proj_W + (size_t)l * 2048 * 1024, WoutT + (size_t)l * 1024 * 2048,
            2048, 1024, 1024);
    }
    transpose_w<<<dim3(1000, 32), 256, 0, stream>>>(head_W, WheadT, 1024, 32000, 32000);
    sinkhorn_k<<<1, 64, 0, stream>>>(mixer_log, Mall);
    embed_gather<<<4096, 256, 0, stream>>>(tokens, embed, H0);

    float* Hc = H0;
    float* Hn = H1;
    for (int l = 0; l < 4; l++) {
        rmsnorm_k<<<4096, 256, 0, stream>>>(Hc, norm_w + l * 1024, un);
        gemm256<<<dim3(16, 19), 512, 0, stream>>>(
            un, WinT + (size_t)l * 4864 * 1024, in_proj_b + l * 4612, zx,
            4096, 4612, 1024);
        dt_cumsum<<<8, 256, 0, stream>>>(zx, dt_bias + l * 4, A_log + l * 4, dtb, cumb, Eb);
        make_xT<<<dim3(32, 8, 8), 256, 0, stream>>>(zx, xT);
        make_BC<<<4096, 256, 0, stream>>>(zx, Bc, Cc);
        chunk_intra<<<dim3(32, 8), 256, 0, stream>>>(Bc, Cc, xT, dtb, cumb, Yb, Hloc);
        chunk_scan<<<dim3(8, 8, 4), 256, 0, stream>>>(Hloc, Eb, HpreT);
        chunk_inter<<<dim3(32, 8), 256, 0, stream>>>(Cc, HpreT, cumb, Eb, Yb, zx, Dp + l * 4, ybuf);
        gemm_f16<<<dim3(32, 8), 256, 0, stream>>>(
            ybuf, WoutT + (size_t)l * 1024 * 2048, out_proj_b + l * 1024, xout,
            4096, 1024, 2048);
        mix_add<<<4096, 256, 0, stream>>>(Hc, xout, Mall + l * 16, Hn);
        float* tmp = Hc; Hc = Hn; Hn = tmp;
    }
    rmsnorm_k<<<4096, 256, 0, stream>>>(Hc, norm_f_w, un);
    gemm256<<<dim3(16, 125), 512, 0, stream>>>(un, WheadT, head_b, out, 4096, 32000, 1024);
}

// Round 4
// 2065.021 us; speedup vs baseline: 1.1009x; 1.0056x over previous
//
#include <hip/hip_runtime.h>
#include <hip/hip_fp16.h>
#include <cstdint>

// ---------------------------------------------------------------------------
// Multi-stream Mamba2-ish LM forward on gfx950.
// All big matmuls: f16 MFMA (16x16x32), f32 accumulate.
// Scan: chunked SSD (chunk Q=64): intra-chunk matmuls + cross-chunk recurrence.
// ---------------------------------------------------------------------------

typedef _Float16 f16;
typedef __attribute__((ext_vector_type(8))) _Float16 f16x8;
typedef __attribute__((ext_vector_type(4))) _Float16 f16x4;
typedef __attribute__((ext_vector_type(4))) float f32x4;

#define LDS_CAST(p) ((__attribute__((address_space(3))) void*)(p))
#define GLB_CAST(p) ((const __attribute__((address_space(1))) void*)(p))

static __device__ __forceinline__ void gload16(const void* g, void* l) {
    __builtin_amdgcn_global_load_lds(GLB_CAST(g), LDS_CAST(l), 16, 0, 0);
}

// ---------------------------------------------------------------------------
// gemm256: C(MxN,f32) = A(MxK,f16) @ Bt(NxK,f16)^T + bias
// 256x256 tile, BK=32, 512 threads (8 waves, 2M x 4N), per-wave 128x64 out.
// T3+T4 (r4: 4-deep): quad-buffered LDS ring (128KB, still 1 block/CU),
// stage 3 K-tiles ahead, 2 phases per K-tile, raw s_barrier, boundary wait
// s_waitcnt vmcnt(8) (drain ONLY the tile needed next; 2 tiles stay in
// flight). Cover = ~2.5 K-tiles of compute > HBM miss latency (~900cy).
// T2 (r3, verified 0 conflicts): bank = 16*(row&1)+4*chunk with
// chunk = ksel ^ ((row>>1)&3); pre-swizzled global source, linear LDS dest.
// T5: setprio(1) around each 16-MFMA cluster.
// Requires: M%256==0, Npad%256==0 (zero-padded Bt rows), K%32==0, K/32>=4.
// ---------------------------------------------------------------------------
__global__ __launch_bounds__(512, 2) void gemm256(
    const f16* __restrict__ A, const f16* __restrict__ Bt,
    const float* __restrict__ bias, float* __restrict__ C,
    int M, int N, int K)
{
    __shared__ f16 AS[4 * 256 * 32];   // 4 slots x (256 rows x 32 f16) = 64KB
    __shared__ f16 BS[4 * 256 * 32];   // 64KB

    const int tid = threadIdx.x;
    const int lane = tid & 63;
    const int w = tid >> 6;
    const int wr = w >> 2;            // 0..1  (M half)
    const int wc = w & 3;             // 0..3  (N quarter)
    const int mrow = lane & 15, ksel = lane >> 4;

    // ---- tile-order swizzle (m204 bijective XCD chunk + GROUP_M=8 m-fast) ---
    const int gx = gridDim.x;         // M tiles
    const int gy = gridDim.y;         // N tiles
    const int nwg = gx * gy;
    int lin = blockIdx.y * gx + blockIdx.x;
    int xcd = lin & 7, loc = lin >> 3;
    int q = nwg >> 3, rr = nwg & 7;
    int wg = (xcd < rr) ? (xcd * (q + 1) + loc)
                        : (rr * (q + 1) + (xcd - rr) * q + loc);
    const int GROUP = 8;
    int per_group = GROUP * gy;
    int gid = wg / per_group;
    int first_m = gid * GROUP;
    int gsz = (gx - first_m < GROUP) ? (gx - first_m) : GROUP;
    int inner = wg - gid * per_group;
    const int m0 = (first_m + inner % gsz) * 256;
    const int n0 = (inner / gsz) * 256;
    // ------------------------------------------------------------------------

    // staging geometry: half-tile = 128 rows x 32 f16 (8KB), 1 gload16/thread.
    // physical LDS cell (row, 16B-chunk c) holds logical chunk c ^ ((row>>1)&3).
    const int rowt = tid >> 2;                             // 0..127
    const int colE = ((tid & 3) ^ ((rowt >> 1) & 3)) * 8;  // pre-swizzled source col
    const int ldst = tid * 8;                              // linear LDS dest (elems)

    const f16* gA = A + (size_t)m0 * K;
    const f16* gB = Bt + (size_t)n0 * K;
    const size_t gofsA0 = (size_t)rowt * K + colE;
    const size_t gofsA1 = (size_t)(128 + rowt) * K + colE;   // +128 keeps row bits 1-2
    const size_t gofsB0 = gofsA0;
    const size_t gofsB1 = gofsA1;

    // fragment read offsets (swizzled): row*32 + (ksel ^ ((row>>1)&3))*8;
    // row bits 1-2 come from mrow only (mf*16, wr*128 are 16-aligned).
    const int fcol = ((ksel ^ ((mrow >> 1) & 3)) * 8);
    int offA[8], offB[4];
#pragma unroll
    for (int mf = 0; mf < 8; mf++)
        offA[mf] = (wr * 128 + mf * 16 + mrow) * 32 + fcol;
#pragma unroll
    for (int nf = 0; nf < 4; nf++)
        offB[nf] = (wc * 64 + nf * 16 + mrow) * 32 + fcol;

    f32x4 zero = {0.f, 0.f, 0.f, 0.f};
    f32x4 acc[8][4];
#pragma unroll
    for (int i = 0; i < 8; i++)
#pragma unroll
        for (int j = 0; j < 4; j++) acc[i][j] = zero;

    const int nt = K >> 5;   // requires nt >= 4

    // ---- prologue: stage tiles 0,1,2 into slots 0,1,2 -----------------------
#pragma unroll
    for (int T = 0; T < 3; ++T) {
        gload16(gA + gofsA0 + (size_t)T * 32, AS + T * 8192 + ldst);
        gload16(gA + gofsA1 + (size_t)T * 32, AS + T * 8192 + 4096 + ldst);
        gload16(gB + gofsB0 + (size_t)T * 32, BS + T * 8192 + ldst);
        gload16(gB + gofsB1 + (size_t)T * 32, BS + T * 8192 + 4096 + ldst);
    }
    asm volatile("s_waitcnt vmcnt(8)" ::: "memory");  // tile 0 resident
    __builtin_amdgcn_sched_barrier(0);
    __builtin_amdgcn_s_barrier();

    // ---- main loop ----------------------------------------------------------
    for (int t = 0; t < nt; ++t) {
        const int slot = t & 3;
        const f16* as = AS + slot * 8192;
        const f16* bs = BS + slot * 8192;
        const int sst = (t + 3) & 3;      // == (t-1)&3: fully consumed last iter
        const bool st = (t + 3) < nt;
        const size_t kof = (size_t)(t + 3) * 32;

        // ---- phase 0: read af[0..3] + bf[0..3]; stage A halves of t+3 -------
        f16x8 af[4], bf[4];
#pragma unroll
        for (int mf = 0; mf < 4; mf++) af[mf] = *(const f16x8*)(as + offA[mf]);
#pragma unroll
        for (int nf = 0; nf < 4; nf++) bf[nf] = *(const f16x8*)(bs + offB[nf]);
        if (st) {
            gload16(gA + gofsA0 + kof, AS + sst * 8192 + ldst);
            gload16(gA + gofsA1 + kof, AS + sst * 8192 + 4096 + ldst);
        }
        __builtin_amdgcn_s_barrier();
        __builtin_amdgcn_s_setprio(1);
#pragma unroll
        for (int mf = 0; mf < 4; mf++)
#pragma unroll
            for (int nf = 0; nf < 4; nf++)
                acc[mf][nf] = __builtin_amdgcn_mfma_f32_16x16x32_f16(bf[nf], af[mf], acc[mf][nf], 0, 0, 0);
        __builtin_amdgcn_s_setprio(0);
        __builtin_amdgcn_s_barrier();

        // ---- phase 1: read af[4..7]; stage B halves of t+3 ------------------
        f16x8 af2[4];
#pragma unroll
        for (int mf = 0; mf < 4; mf++) af2[mf] = *(const f16x8*)(as + offA[4 + mf]);
        if (st) {
            gload16(gB + gofsB0 + kof, BS + sst * 8192 + ldst);
            gload16(gB + gofsB1 + kof, BS + sst * 8192 + 4096 + ldst);
        }
        __builtin_amdgcn_s_barrier();
        __builtin_amdgcn_s_setprio(1);
#pragma unroll
        for (int mf = 0; mf < 4; mf++)
#pragma unroll
            for (int nf = 0; nf < 4; nf++)
                acc[4 + mf][nf] = __builtin_amdgcn_mfma_f32_16x16x32_f16(bf[nf], af2[mf], acc[4 + mf][nf], 0, 0, 0);
        __builtin_amdgcn_s_setprio(0);

        // ---- K-tile boundary: counted drain, only the next tile -------------
        // outstanding-allowed = 4 * min(2, nt-t-2)
        if (t + 1 < nt) {
            const int rem = nt - t - 2;
            if (rem >= 2) {
                asm volatile("s_waitcnt vmcnt(8)" ::: "memory");
            } else if (rem == 1) {
                asm volatile("s_waitcnt vmcnt(4)" ::: "memory");
            } else {
                asm volatile("s_waitcnt vmcnt(0)" ::: "memory");
            }
            __builtin_amdgcn_sched_barrier(0);
            __builtin_amdgcn_s_barrier();
        }
    }

    // ---- epilogue: float4 stores (acc regs walk 4 consecutive n) ------------
#pragma unroll
    for (int mf = 0; mf < 8; mf++) {
        int m = m0 + wr * 128 + mf * 16 + mrow;
#pragma unroll
        for (int nf = 0; nf < 4; nf++) {
            int nb = n0 + wc * 64 + nf * 16 + ksel * 4;
            if (nb < N) {
                float4 bv = {0.f, 0.f, 0.f, 0.f};
                if (bias) bv = *(const float4*)(bias + nb);
                float4 v;
                v.x = acc[mf][nf][0] + bv.x;
                v.y = acc[mf][nf][1] + bv.y;
                v.z = acc[mf][nf][2] + bv.z;
                v.w = acc[mf][nf][3] + bv.w;
                *(float4*)(C + (size_t)m * N + nb) = v;
            }
        }
    }
}

// ---------------------------------------------------------------------------
// Generic f16 GEMM (128x128 tile, m97 structure) — kept for out-proj (N=1024).
// ---------------------------------------------------------------------------
__global__ __launch_bounds__(256) void gemm_f16(
    const f16* __restrict__ A, const f16* __restrict__ Bt,
    const float* __restrict__ bias, float* __restrict__ C,
    int M, int N, int K)
{
    __shared__ f16 As[128 * 32];
    __shared__ f16 Bs[128 * 32];
    const int t = threadIdx.x;
    const int lane = t & 63;
    const int w = t >> 6;

    const int gx = gridDim.x;            // M tiles
    const int gy = gridDim.y;            // N tiles
    const int nwg = gx * gy;
    int lin = blockIdx.y * gx + blockIdx.x;
    int xcd = lin & 7, loc = lin >> 3;
    int q = nwg >> 3, rr = nwg & 7;
    int wg = (xcd < rr) ? (xcd * (q + 1) + loc)
                        : (rr * (q + 1) + (xcd - rr) * q + loc);
    const int GROUP = 8;
    int per_group = GROUP * gy;
    int gid = wg / per_group;
    int first_m = gid * GROUP;
    int gsz = (gx - first_m < GROUP) ? (gx - first_m) : GROUP;
    int inner = wg - gid * per_group;
    const int m0 = (first_m + inner % gsz) * 128;
    const int n0 = (inner / gsz) * 128;

    const int wm0 = (w >> 1) * 64, wn0 = (w & 1) * 64;
    const int mrow = lane & 15, ksel = lane >> 4;

    f32x4 zero = {0.f, 0.f, 0.f, 0.f};
    f32x4 acc[4][4];
#pragma unroll
    for (int i = 0; i < 4; i++)
#pragma unroll
        for (int j = 0; j < 4; j++) acc[i][j] = zero;

    const f16* Abase = A + (size_t)m0 * K;
    const f16* Bbase = Bt + (size_t)n0 * K;

    for (int k0 = 0; k0 < K; k0 += 32) {
#pragma unroll
        for (int i = 0; i < 2; i++) {
            int lin2 = t + i * 256;
            int r = lin2 >> 2;
            int cc = (lin2 & 3) * 8;
            gload16(Abase + (size_t)r * K + k0 + cc, As + lin2 * 8);
            gload16(Bbase + (size_t)r * K + k0 + cc, Bs + lin2 * 8);
        }
        __syncthreads();
        f16x8 af[4], bf[4];
#pragma unroll
        for (int i = 0; i < 4; i++) {
            af[i] = *(const f16x8*)(As + (wm0 + i * 16 + mrow) * 32 + ksel * 8);
            bf[i] = *(const f16x8*)(Bs + (wn0 + i * 16 + mrow) * 32 + ksel * 8);
        }
#pragma unroll
        for (int i = 0; i < 4; i++)
#pragma unroll
            for (int j = 0; j < 4; j++)
                acc[i][j] = __builtin_amdgcn_mfma_f32_16x16x32_f16(bf[j], af[i], acc[i][j], 0, 0, 0);
        __syncthreads();
    }

#pragma unroll
    for (int i = 0; i < 4; i++) {
        int m = m0 + wm0 + i * 16 + mrow;
#pragma unroll
        for (int j = 0; j < 4; j++) {
            int nb = n0 + wn0 + j * 16 + ksel * 4;
            if (nb < N) {
                float4 bv = {0.f, 0.f, 0.f, 0.f};
                if (bias) bv = *(const float4*)(bias + nb);
                float4 v;
                v.x = acc[i][j][0] + bv.x;
                v.y = acc[i][j][1] + bv.y;
                v.z = acc[i][j][2] + bv.z;
                v.w = acc[i][j][3] + bv.w;
                *(float4*)(C + (size_t)m * N + nb) = v;
            }
        }
    }
}

// ---------------------------------------------------------------------------
// Weight convert+transpose: W(KxN,f32) -> Wt(NpadxK,f16), zero-filled pad rows.
// ---------------------------------------------------------------------------
__global__ __launch_bounds__(256) void transpose_w(
    const float* __restrict__ W, f16* __restrict__ Wt, int K, int N, int Npad)
{
    __shared__ float tile[32][33];
    int n0 = blockIdx.x * 32, k0 = blockIdx.y * 32;
    int tx = threadIdx.x & 31, ty = threadIdx.x >> 5;
#pragma unroll
    for (int i = 0; i < 4; i++) {
        int k = k0 + ty + 8 * i;
        int n = n0 + tx;
        tile[ty + 8 * i][tx] = (n < N) ? W[(size_t)k * N + n] : 0.f;
    }
    __syncthreads();
#pragma unroll
    for (int i = 0; i < 4; i++) {
        int n = n0 + ty + 8 * i;
        if (n < Npad) Wt[(size_t)n * K + k0 + tx] = (f16)tile[tx][ty + 8 * i];
    }
}

// ---------------------------------------------------------------------------
// Sinkhorn on 4x4 mixer logits, all 4 layers; single thread (trivial work).
// ---------------------------------------------------------------------------
__global__ void sinkhorn_k(const float* __restrict__ logits, float* __restrict__ Mout)
{
    if (threadIdx.x != 0 || blockIdx.x != 0) return;
    for (int l = 0; l < 4; l++) {
        float M[16];
        for (int i = 0; i < 16; i++) {
            float v = logits[l * 16 + i];
            M[i] = 1.f / (1.f + __expf(-v)) + ((i % 5) == 0 ? 1.f : 0.f);
        }
        for (int it = 0; it < 5; it++) {
            for (int r = 0; r < 4; r++) {
                float s = M[r*4] + M[r*4+1] + M[r*4+2] + M[r*4+3] + 1e-6f;
                for (int c = 0; c < 4; c++) M[r*4+c] /= s;
            }
            for (int c = 0; c < 4; c++) {
                float s = M[c] + M[4+c] + M[8+c] + M[12+c] + 1e-6f;
                for (int r = 0; r < 4; r++) M[r*4+c] /= s;
            }
        }
        for (int i = 0; i < 16; i++) Mout[l * 16 + i] = M[i];
    }
}

__global__ __launch_bounds__(256) void embed_gather(
    const int* __restrict__ tokens, const float* __restrict__ embed, float* __restrict__ H)
{
    int i = blockIdx.x * 256 + threadIdx.x;
    int tok = i >> 8, d4 = i & 255;
    int tk = tokens[tok];
    float4 v = ((const float4*)(embed + (size_t)tk * 1024))[d4];
    ((float4*)(H + (size_t)tok * 1024))[d4] = v;
}

// RMSNorm over d=1024, one block per token, f16 output for GEMM A-operand.
__global__ __launch_bounds__(256) void rmsnorm_k(
    const float* __restrict__ X, const float* __restrict__ w, f16* __restrict__ out)
{
    int tok = blockIdx.x;
    int t = threadIdx.x;
    const float4 v = ((const float4*)(X + (size_t)tok * 1024))[t];
    float ss = v.x*v.x + v.y*v.y + v.z*v.z + v.w*v.w;
#pragma unroll
    for (int off = 32; off > 0; off >>= 1) ss += __shfl_down(ss, off, 64);
    __shared__ float wsum[4];
    if ((t & 63) == 0) wsum[t >> 6] = ss;
    __syncthreads();
    float tot = wsum[0] + wsum[1] + wsum[2] + wsum[3];
    float sc = rsqrtf(tot * (1.f / 1024.f) + 1.1920929e-07f);
    const float4 wv = ((const float4*)w)[t];
    f16x4 o;
    o[0] = (f16)(v.x * sc * wv.x);
    o[1] = (f16)(v.y * sc * wv.y);
    o[2] = (f16)(v.z * sc * wv.z);
    o[3] = (f16)(v.w * sc * wv.w);
    ((f16x4*)(out + (size_t)tok * 1024))[t] = o;
}

// ---------------------------------------------------------------------------
// dt = softplus(dt_raw + bias); cum = inclusive prefix of dt*A per (b,h);
// E[c] = cum at chunk ends. One block per (b,h).
// ---------------------------------------------------------------------------
__global__ __launch_bounds__(256) void dt_cumsum(
    const float* __restrict__ zx, const float* __restrict__ dt_bias,
    const float* __restrict__ A_log,
    float* __restrict__ dt, float* __restrict__ cum, float* __restrict__ E)
{
    int bh = blockIdx.x;
    int b = bh >> 2, h = bh & 3;
    int t = threadIdx.x;
    float Ah = -__expf(A_log[h]);
    float bias = dt_bias[h];
    float run = 0.f, vals[8];
    for (int i = 0; i < 8; i++) {
        int l = t * 8 + i;
        float raw = zx[((size_t)(b * 2048 + l)) * 4612 + 4096 + h] + bias;
        float dtv = (raw > 20.f) ? raw : log1pf(__expf(raw));
        dt[bh * 2048 + l] = dtv;
        run += dtv * Ah;
        vals[i] = run;
    }
    __shared__ float ps[256];
    ps[t] = run;
    __syncthreads();
    for (int off = 1; off < 256; off <<= 1) {
        float v = (t >= off) ? ps[t - off] : 0.f;
        __syncthreads();
        ps[t] += v;
        __syncthreads();
    }
    float offset = (t > 0) ? ps[t - 1] : 0.f;
    for (int i = 0; i < 8; i++) {
        int l = t * 8 + i;
        float cv = vals[i] + offset;
        cum[bh * 2048 + l] = cv;
        if ((l & 63) == 63) E[bh * 32 + (l >> 6)] = cv;
    }
}

// x slice of zxbcdt (f32) -> xT (B,H,P,L) f16 (transposed, L-contiguous)
__global__ __launch_bounds__(256) void make_xT(
    const float* __restrict__ zx, f16* __restrict__ xT)
{
    int lb = blockIdx.x * 64, pb = blockIdx.y * 64, bh = blockIdx.z;
    int b = bh >> 2, h = bh & 3;
    __shared__ float tile[64][65];
    int tx = threadIdx.x & 63, ty = threadIdx.x >> 6; // 64 x 4
#pragma unroll
    for (int i = 0; i < 16; i++) {
        int ll = ty + 4 * i;
        tile[ll][tx] = zx[((size_t)(b * 2048 + lb + ll)) * 4612 + 2048 + h * 512 + pb + tx];
    }
    __syncthreads();
#pragma unroll
    for (int i = 0; i < 16; i++) {
        int pl = ty + 4 * i;
        xT[((size_t)bh * 512 + pb + pl) * 2048 + lb + tx] = (f16)tile[tx][pl];
    }
}

// B,C slices -> (B,H,L,64) f16
__global__ __launch_bounds__(256) void make_BC(
    const float* __restrict__ zx, f16* __restrict__ Bc, f16* __restrict__ Cc)
{
    int i = blockIdx.x * 256 + threadIdx.x; // over B*L*H*64 = 1M
    int n = i & 63, h = (i >> 6) & 3, l = (i >> 8) & 2047, b = i >> 19;
    size_t rowoff = ((size_t)(b * 2048 + l)) * 4612 + 4100 + h * 128;
    size_t o = (((size_t)(b * 4 + h)) * 2048 + l) * 64 + n;
    Bc[o] = (f16)zx[rowoff + n];
    Cc[o] = (f16)zx[rowoff + 64 + n];
}

// ---------------------------------------------------------------------------
// Intra-chunk: per (c, bh) block.
//   S[t][s] = (s<=t) ? (C_t.B_s)*exp(cum_t-cum_s)*dt_s : 0
//   W[n][s] = B_s[n]*exp(cumEnd-cum_s)*dt_s
//   Y_intra = S @ X   (64x64 @ 64x512)
//   Hloc    = W @ X   (64x64 @ 64x512)
// ---------------------------------------------------------------------------
__global__ __launch_bounds__(256) void chunk_intra(
    const f16* __restrict__ Bc, const f16* __restrict__ Cc,
    const f16* __restrict__ xT,
    const float* __restrict__ dt, const float* __restrict__ cum,
    float* __restrict__ Y, float* __restrict__ Hloc)
{
    int c = blockIdx.x, bh = blockIdx.y;
    int l0 = c * 64;
    __shared__ f16 Cs[4096], Bs2[4096], Sb[4096], Wb[4096];
    __shared__ float cums[64], dts[64];
    int t = threadIdx.x;
    {
        const f16x8* sC = (const f16x8*)(Cc + ((size_t)bh * 2048 + l0) * 64);
        const f16x8* sB = (const f16x8*)(Bc + ((size_t)bh * 2048 + l0) * 64);
        ((f16x8*)Cs)[t] = sC[t];
        ((f16x8*)Cs)[t + 256] = sC[t + 256];
        ((f16x8*)Bs2)[t] = sB[t];
        ((f16x8*)Bs2)[t + 256] = sB[t + 256];
    }
    if (t < 64) {
        cums[t] = cum[bh * 2048 + l0 + t];
        dts[t] = dt[bh * 2048 + l0 + t];
    }
    __syncthreads();
    float cumEnd = cums[63];
    int lane = t & 63, w = t >> 6;
    int mrow = lane & 15, ksel = lane >> 4;

    // ---- S = tril(C @ B^T) * decay via MFMA; wave w owns rows w*16..w*16+15
    {
        f16x8 cf[2];
        cf[0] = *(const f16x8*)(Cs + (w * 16 + mrow) * 64 + ksel * 8);
        cf[1] = *(const f16x8*)(Cs + (w * 16 + mrow) * 64 + 32 + ksel * 8);
#pragma unroll
        for (int j = 0; j < 4; j++) {
            f32x4 d = {0.f, 0.f, 0.f, 0.f};
#pragma unroll
            for (int ks = 0; ks < 2; ks++) {
                f16x8 bfv = *(const f16x8*)(Bs2 + (j * 16 + mrow) * 64 + ks * 32 + ksel * 8);
                d = __builtin_amdgcn_mfma_f32_16x16x32_f16(cf[ks], bfv, d, 0, 0, 0);
            }
            int ss = j * 16 + mrow;
#pragma unroll
            for (int r = 0; r < 4; r++) {
                int tt = w * 16 + ksel * 4 + r;
                float sv = (ss <= tt) ? d[r] * __expf(cums[tt] - cums[ss]) * dts[ss] : 0.f;
                Sb[tt * 64 + ss] = (f16)sv;
            }
        }
#pragma unroll
        for (int q2 = 0; q2 < 16; q2++) {
            int idx = t * 16 + q2;
            int tt = idx >> 6, ss = idx & 63;
            float wv = (float)Bs2[ss * 64 + tt] * __expf(cumEnd - cums[ss]) * dts[ss];
            Wb[tt * 64 + ss] = (f16)wv;
        }
    }
    __syncthreads();

    f16x8 sfr[2][4], wfr[2][4];
#pragma unroll
    for (int ks = 0; ks < 2; ks++)
#pragma unroll
        for (int mt = 0; mt < 4; mt++) {
            sfr[ks][mt] = *(const f16x8*)(Sb + (mt * 16 + mrow) * 64 + ks * 32 + ksel * 8);
            wfr[ks][mt] = *(const f16x8*)(Wb + (mt * 16 + mrow) * 64 + ks * 32 + ksel * 8);
        }
    const f16* xbase = xT + ((size_t)bh * 512) * 2048 + c * 64;
    f32x4 zero = {0.f, 0.f, 0.f, 0.f};
#pragma unroll
    for (int ph = 0; ph < 2; ph++) {
        int pb = w * 128 + ph * 64;
        f32x4 aY[4][4], aH[4][4];
#pragma unroll
        for (int i = 0; i < 4; i++)
#pragma unroll
            for (int j = 0; j < 4; j++) { aY[i][j] = zero; aH[i][j] = zero; }
#pragma unroll
        for (int ks = 0; ks < 2; ks++) {
#pragma unroll
            for (int nt = 0; nt < 4; nt++) {
                int pp = pb + nt * 16 + mrow;
                f16x8 bfv = *(const f16x8*)(xbase + (size_t)pp * 2048 + ks * 32 + ksel * 8);
#pragma unroll
                for (int mt = 0; mt < 4; mt++) {
                    aY[mt][nt] = __builtin_amdgcn_mfma_f32_16x16x32_f16(sfr[ks][mt], bfv, aY[mt][nt], 0, 0, 0);
                    aH[mt][nt] = __builtin_amdgcn_mfma_f32_16x16x32_f16(wfr[ks][mt], bfv, aH[mt][nt], 0, 0, 0);
                }
            }
        }
        int r0 = ksel * 4;
#pragma unroll
        for (int mt = 0; mt < 4; mt++)
#pragma unroll
            for (int nt = 0; nt < 4; nt++) {
                int pp = pb + nt * 16 + mrow;
#pragma unroll
                for (int r = 0; r < 4; r++) {
                    int tt = mt * 16 + r0 + r;
                    Y[((size_t)bh * 2048 + l0 + tt) * 512 + pp] = aY[mt][nt][r];
                    Hloc[(((size_t)bh * 32 + c) * 64 + tt) * 512 + pp] = aH[mt][nt][r];
                }
            }
    }
}

// ---------------------------------------------------------------------------
// Cross-chunk recurrence. Thread owns (p, 4 n's) of one bh. Writes the state
// BEFORE chunk c as HpreT (BH,32,512,64) f16.
// ---------------------------------------------------------------------------
__global__ __launch_bounds__(256) void chunk_scan(
    const float* __restrict__ Hloc, const float* __restrict__ E,
    f16* __restrict__ HpreT)
{
    int bh = blockIdx.y;
    int p = blockIdx.x * 64 + (threadIdx.x & 63);
    int nb = blockIdx.z * 16 + (threadIdx.x >> 6) * 4;
    float h[4];
#pragma unroll
    for (int j = 0; j < 4; j++) h[j] = 0.f;
    float Eprev = 0.f;
    for (int c = 0; c < 32; c++) {
        size_t ob = (((size_t)bh * 32 + c) * 512 + p) * 64 + nb;
        f16x4 v;
#pragma unroll
        for (int j = 0; j < 4; j++) v[j] = (f16)h[j];
        *(f16x4*)(HpreT + ob) = v;
        float Ec = E[bh * 32 + c];
        float decay = __expf(Ec - Eprev);
        Eprev = Ec;
        size_t ib = (((size_t)bh * 32 + c) * 64 + nb) * 512 + p;
#pragma unroll
        for (int j = 0; j < 4; j++)
            h[j] = decay * h[j] + Hloc[ib + (size_t)j * 512];
    }
}

// ---------------------------------------------------------------------------
// Inter-chunk Y += Chat @ Hpre, then fused epilogue:
//   y = Y_intra + Y_inter + x*D; out = y * silu(z)  -> ybuf f16 (B*L, 2048)
// ---------------------------------------------------------------------------
__global__ __launch_bounds__(256) void chunk_inter(
    const f16* __restrict__ Cc, const f16* __restrict__ HpreT,
    const float* __restrict__ cum, const float* __restrict__ E,
    const float* __restrict__ Y, const float* __restrict__ zx,
    const float* __restrict__ Dp, f16* __restrict__ ybuf)
{
    int c = blockIdx.x, bh = blockIdx.y;
    int b = bh >> 2, h = bh & 3;
    int l0 = c * 64;
    __shared__ f16 Chat[4096];
    int t = threadIdx.x;
    float Eprev = (c > 0) ? E[bh * 32 + c - 1] : 0.f;
    for (int i = t; i < 4096; i += 256) {
        int tt = i >> 6, n = i & 63;
        float cv = (float)Cc[((size_t)bh * 2048 + l0 + tt) * 64 + n];
        Chat[i] = (f16)(cv * __expf(cum[bh * 2048 + l0 + tt] - Eprev));
    }
    __syncthreads();
    int lane = t & 63, w = t >> 6;
    int mrow = lane & 15, ksel = lane >> 4;
    float Dh = Dp[h];
    f16x8 af[2][4];
#pragma unroll
    for (int ks = 0; ks < 2; ks++)
#pragma unroll
        for (int mt = 0; mt < 4; mt++)
            af[ks][mt] = *(const f16x8*)(Chat + (mt * 16 + mrow) * 64 + ks * 32 + ksel * 8);
    const f16* hb = HpreT + (((size_t)bh * 32 + c) * 512) * 64;
    f32x4 zero = {0.f, 0.f, 0.f, 0.f};
#pragma unroll
    for (int ph = 0; ph < 2; ph++) {
        int pb = w * 128 + ph * 64;
        f32x4 acc[4][4];
#pragma unroll
        for (int i = 0; i < 4; i++)
#pragma unroll
            for (int j = 0; j < 4; j++) acc[i][j] = zero;
#pragma unroll
        for (int ks = 0; ks < 2; ks++) {
#pragma unroll
            for (int nt = 0; nt < 4; nt++) {
                int pp = pb + nt * 16 + mrow;
                f16x8 bfv = *(const f16x8*)(hb + (size_t)pp * 64 + ks * 32 + ksel * 8);
#pragma unroll
                for (int mt = 0; mt < 4; mt++)
                    acc[mt][nt] = __builtin_amdgcn_mfma_f32_16x16x32_f16(af[ks][mt], bfv, acc[mt][nt], 0, 0, 0);
            }
        }
        int r0 = ksel * 4;
#pragma unroll
        for (int mt = 0; mt < 4; mt++)
#pragma unroll
            for (int nt = 0; nt < 4; nt++) {
                int pp = pb + nt * 16 + mrow;
#pragma unroll
                for (int r = 0; r < 4; r++) {
                    int tt = mt * 16 + r0 + r;
                    int l = l0 + tt;
                    size_t zrow = ((size_t)(b * 2048 + l)) * 4612;
                    float y = acc[mt][nt][r] + Y[((size_t)bh * 2048 + l) * 512 + pp];
                    float x = zx[zrow + 2048 + h * 512 + pp];
                    y += x * Dh;
                    float z = zx[zrow + h * 512 + pp];
                    float sig = 1.f / (1.f + __expf(-z));
                    ybuf[((size_t)(b * 2048 + l)) * 2048 + h * 512 + pp] = (f16)(y * z * sig);
                }
            }
    }
}

// H_new[tok, s*256+j] = sum_i M[s][i]*H_old[tok, i*256+j] + xout[tok, s*256+j]
__global__ __launch_bounds__(256) void mix_add(
    const float* __restrict__ Hold, const float* __restrict__ xout,
    const float* __restrict__ Mm, float* __restrict__ Hnew)
{
    int i = blockIdx.x * 256 + threadIdx.x;
    int j = i & 255, tok = i >> 8;
    size_t rb = (size_t)tok * 1024;
    float h0 = Hold[rb + j], h1 = Hold[rb + 256 + j];
    float h2 = Hold[rb + 512 + j], h3 = Hold[rb + 768 + j];
#pragma unroll
    for (int s = 0; s < 4; s++) {
        float v = Mm[s*4+0]*h0 + Mm[s*4+1]*h1 + Mm[s*4+2]*h2 + Mm[s*4+3]*h3
                + xout[rb + s * 256 + j];
        Hnew[rb + s * 256 + j] = v;
    }
}

// ---------------------------------------------------------------------------
extern "C" void kernel_launch(void* const* d_in, const int* in_sizes, int n_in,
                              void* d_out, int out_size, void* d_ws, size_t ws_size,
                              hipStream_t stream)
{
    const int*   tokens     = (const int*)d_in[0];
    const float* embed      = (const float*)d_in[1];
    const float* norm_w     = (const float*)d_in[2];
    const float* in_proj_W  = (const float*)d_in[3];
    const float* in_proj_b  = (const float*)d_in[4];
    const float* A_log      = (const float*)d_in[5];
    const float* Dp         = (const float*)d_in[6];
    const float* dt_bias    = (const float*)d_in[7];
    const float* out_proj_W = (const float*)d_in[8];
    const float* out_proj_b = (const float*)d_in[9];
    const float* mixer_log  = (const float*)d_in[10];
    const float* norm_f_w   = (const float*)d_in[11];
    const float* head_W     = (const float*)d_in[12];
    const float* head_b     = (const float*)d_in[13];
    float* out = (float*)d_out;
    (void)in_sizes; (void)n_in; (void)out_size; (void)ws_size;

    char* base = (char*)d_ws;
    size_t off = 0;
    auto alloc = [&](size_t bytes) -> void* {
        void* r = (void*)(base + off);
        off = (off + bytes + 255) & ~(size_t)255;
        return r;
    };
    f16*   WinT   = (f16*)alloc(4ull * 4864 * 1024 * 2);   // Npad 4864 (19 x 256)
    f16*   WoutT  = (f16*)alloc(4ull * 1024 * 2048 * 2);
    f16*   WheadT = (f16*)alloc(32000ull * 1024 * 2);
    float* Mall   = (float*)alloc(64 * 4);
    float* H0     = (float*)alloc(4096ull * 1024 * 4);
    float* H1     = (float*)alloc(4096ull * 1024 * 4);
    f16*   un     = (f16*)alloc(4096ull * 1024 * 2);
    float* zx     = (float*)alloc(4096ull * 4612 * 4);
    float* dtb    = (float*)alloc(8ull * 2048 * 4);
    float* cumb   = (float*)alloc(8ull * 2048 * 4);
    float* Eb     = (float*)alloc(8ull * 32 * 4);
    f16*   xT     = (f16*)alloc(8ull * 512 * 2048 * 2);
    f16*   Bc     = (f16*)alloc(8ull * 2048 * 64 * 2);
    f16*   Cc     = (f16*)alloc(8ull * 2048 * 64 * 2);
    float* Yb     = (float*)alloc(8ull * 2048 * 512 * 4);
    float* Hloc   = (float*)alloc(8ull * 32 * 64 * 512 * 4);
    f16*   HpreT  = (f16*)alloc(8ull * 32 * 512 * 64 * 2);
    f16*   ybuf   = (f16*)alloc(4096ull * 2048 * 2);
    float* xout   = (float*)alloc(4096ull * 1024 * 4);

    // Weight conversion (every call; inputs are re-restored by harness)
    for (int l = 0; l < 4; l++) {
        transpose_w<<<dim3(152, 32), 256, 0, stream>>>(
            in_proj_W + (size_t)l * 1024 * 4612, WinT + (size_t)l * 4864 * 1024,
            1024, 4612, 4864);
        transpose_w<<<dim3(32, 64), 256, 0, stream>>>(
            out_proj_W + (size_t)l * 2048 * 1024, WoutT + (size_t)l * 1024 * 2048,
            2048, 1024, 1024);
    }
    transpose_w<<<dim3(1000, 32), 256, 0, stream>>>(head_W, WheadT, 1024, 32000, 32000);
    sinkhorn_k<<<1, 64, 0, stream>>>(mixer_log, Mall);
    embed_gather<<<4096, 256, 0, stream>>>(tokens, embed, H0);

    float* Hc = H0;
    float* Hn = H1;
    for (int l = 0; l < 4; l++) {
        rmsnorm_k<<<4096, 256, 0, stream>>>(Hc, norm_w + l * 1024, un);
        gemm256<<<dim3(16, 19), 512, 0, stream>>>(
            un, WinT + (size_t)l * 4864 * 1024, in_proj_b + l * 4612, zx,
            4096, 4612, 1024);
        dt_cumsum<<<8, 256, 0, stream>>>(zx, dt_bias + l * 4, A_log + l * 4, dtb, cumb, Eb);
        make_xT<<<dim3(32, 8, 8), 256, 0, stream>>>(zx, xT);
        make_BC<<<4096, 256, 0, stream>>>(zx, Bc, Cc);
        chunk_intra<<<dim3(32, 8), 256, 0, stream>>>(Bc, Cc, xT, dtb, cumb, Yb, Hloc);
        chunk_scan<<<dim3(8, 8, 4), 256, 0, stream>>>(Hloc, Eb, HpreT);
        chunk_inter<<<dim3(32, 8), 256, 0, stream>>>(Cc, HpreT, cumb, Eb, Yb, zx, Dp + l * 4, ybuf);
        gemm_f16<<<dim3(32, 8), 256, 0, stream>>>(
            ybuf, WoutT + (size_t)l * 1024 * 2048, out_proj_b + l * 1024, xout,
            4096, 1024, 2048);
        mix_add<<<4096, 256, 0, stream>>>(Hc, xout, Mall + l * 16, Hn);
        float* tmp = Hc; Hc = Hn; Hn = tmp;
    }
    rmsnorm_k<<<4096, 256, 0, stream>>>(Hc, norm_f_w, un);
    gemm256<<<dim3(16, 125), 512, 0, stream>>>(un, WheadT, head_b, out, 4096, 32000, 1024);
}